// Round 4
// baseline (683.626 us; speedup 1.0000x reference)
//
#include <hip/hip_runtime.h>
#include <hip/hip_bf16.h>

typedef __attribute__((ext_vector_type(8))) short short8;
typedef __attribute__((ext_vector_type(4))) short short4v;
typedef __attribute__((ext_vector_type(4))) float floatx4;

#define GLOBAL_AS __attribute__((address_space(1)))
#define LDS_AS    __attribute__((address_space(3)))

__device__ __forceinline__ unsigned short f2bf_rne(float x) {
  unsigned int u = __float_as_uint(x);
  u += 0x7fffu + ((u >> 16) & 1u);
  return (unsigned short)(u >> 16);
}

// ---------------- device helpers for fused prep kernels ----------------
__device__ __forceinline__ void cast8_body(const float* __restrict__ in,
                                           unsigned short* __restrict__ out,
                                           int blk, int n8) {
  int i = blk * 256 + threadIdx.x;
  if (i >= n8) return;
  const float4* p = (const float4*)in;
  float4 v0 = p[2 * i], v1 = p[2 * i + 1];
  short8 o;
  o[0] = (short)f2bf_rne(v0.x); o[1] = (short)f2bf_rne(v0.y);
  o[2] = (short)f2bf_rne(v0.z); o[3] = (short)f2bf_rne(v0.w);
  o[4] = (short)f2bf_rne(v1.x); o[5] = (short)f2bf_rne(v1.y);
  o[6] = (short)f2bf_rne(v1.z); o[7] = (short)f2bf_rne(v1.w);
  *(short8*)(out + 8 * (size_t)i) = o;
}

__device__ __forceinline__ void trans32_body(const float* __restrict__ in,
                                             unsigned short* __restrict__ out,
                                             int R, int C, int bx, int by) {
  __shared__ unsigned short tile[32][33];
  int tx = threadIdx.x & 31, ty = threadIdx.x >> 5;
  int r0 = by * 32, c0 = bx * 32;
#pragma unroll
  for (int j = 0; j < 32; j += 8)
    tile[ty + j][tx] = f2bf_rne(in[(size_t)(r0 + ty + j) * C + c0 + tx]);
  __syncthreads();
#pragma unroll
  for (int j = 0; j < 32; j += 8)
    out[(size_t)(c0 + ty + j) * R + r0 + tx] = tile[tx][ty + j];
}

// ---------------- prep1: cast gf, cast Wg, transpose Gs, bias1 accumulate ----------
// bias1 must be pre-initialized to bgs via hipMemcpyAsync before this launch.
__global__ void prep1_kernel(const float* __restrict__ gf, unsigned short* __restrict__ gf_bf,
                             const float* __restrict__ Wg, unsigned short* __restrict__ Wg_bf,
                             const float* __restrict__ Gs, unsigned short* __restrict__ GsT,
                             const float* __restrict__ bg, float* __restrict__ bias1) {
  const int b = blockIdx.x;
  if (b < 12544) {
    cast8_body(gf, gf_bf, b, 3211264);
  } else if (b < 20736) {
    cast8_body(Wg, Wg_bf, b - 12544, 2097152);
  } else if (b < 24832) {
    int bb = b - 20736;                       // 4096 blocks: 32 col-tiles x 128 row-tiles
    trans32_body(Gs, GsT, 4096, 1024, bb & 31, bb >> 5);
  } else {
    int bb = b - 24832;                       // 64 blocks: 4 j-chunks x 16 k-chunks
    int j = (bb & 3) * 256 + threadIdx.x;
    int k0 = (bb >> 2) * 256;
    float acc = 0.f;
    for (int k = 0; k < 256; ++k) acc += bg[k0 + k] * Gs[(size_t)(k0 + k) * 1024 + j];
    atomicAdd(&bias1[j], acc);
  }
}

// ---------------- prep2: transpose Wgs, dec = sth @ Wdec + bdec, zero scores --------
__global__ void prep2_kernel(const float* __restrict__ Wgs, unsigned short* __restrict__ WgsT,
                             const float* __restrict__ sth, const float* __restrict__ Wdec,
                             const float* __restrict__ bdec, float* __restrict__ dec,
                             float* __restrict__ scores) {
  const int b = blockIdx.x;
  if (b < 1024) {
    trans32_body(Wgs, WgsT, 1024, 1024, b & 31, b >> 5);
  } else if (b < 1040) {
    int bb = b - 1024;                        // 16 blocks: 4 j-chunks x 4 row-groups
    int j = (bb & 3) * 256 + threadIdx.x;
    int r0 = (bb >> 2) * 8;
    float acc[8];
    const float bd = bdec[j];
#pragma unroll
    for (int r = 0; r < 8; ++r) acc[r] = bd;
    for (int k = 0; k < 1024; ++k) {
      float w = Wdec[(size_t)k * 1024 + j];
#pragma unroll
      for (int r = 0; r < 8; ++r) acc[r] += sth[(r0 + r) * 1024 + k] * w;
    }
#pragma unroll
    for (int r = 0; r < 8; ++r) dec[(r0 + r) * 1024 + j] = acc[r];
  } else {
    int i = (b - 1040) * 256 + threadIdx.x;   // 7 blocks zero 1568 float4 = 6272 floats
    if (i < 1568) ((float4*)scores)[i] = make_float4(0.f, 0.f, 0.f, 0.f);
  }
}

// ---------------- split-K reduce: gstar = p0 + p1 + bias1 (f32 in-place + bf16) -----
__global__ __launch_bounds__(256) void reduce2_kernel(const float* __restrict__ p0,
                                                      const float* __restrict__ p1,
                                                      const float* __restrict__ bias,
                                                      float* __restrict__ gf32,
                                                      unsigned short* __restrict__ gb16) {
  const int i = blockIdx.x * 256 + threadIdx.x;     // 6272 blocks -> i < 1,605,632
  float4 a = ((const float4*)p0)[i];
  float4 b = ((const float4*)p1)[i];
  float4 bv = ((const float4*)bias)[i & 255];       // row stride 1024 floats = 256 float4
  float4 r;
  r.x = a.x + b.x + bv.x; r.y = a.y + b.y + bv.y;
  r.z = a.z + b.z + bv.z; r.w = a.w + b.w + bv.w;
  ((float4*)gf32)[i] = r;                           // in-place over p0 (same thread)
  short4v o;
  o[0] = (short)f2bf_rne(r.x); o[1] = (short)f2bf_rne(r.y);
  o[2] = (short)f2bf_rne(r.z); o[3] = (short)f2bf_rne(r.w);
  *(short4v*)(gb16 + 4 * (size_t)i) = o;
}

// ---------------- tiled GEMM, BK=64, double-buffered LDS: C = A @ BT^T --------------
// Round-2 proven structure (2-phase drain dbuf). Split-K via blockIdx.z: each z-plane
// covers Ksub of K, writing f32 partials to Cf + z*csplit (GEMM2) or bf16 direct
// (GEMM1, gridDim.z=1). XCD-chunked swizzle per z-plane; SWAPXY as before.
template <int BM, int BN, bool WRITE_F32, bool WRITE_BF16, bool SWAPXY>
__global__ __launch_bounds__(256, 2) void gemm_tile_kernel(
    const unsigned short* __restrict__ A, const unsigned short* __restrict__ BT,
    float* __restrict__ Cf, unsigned short* __restrict__ Cb,
    int M, int N, int K, int Ksub, size_t csplit) {
  constexpr int AF = BM / 32;
  constexpr int BF = BN / 32;
  constexpr int ASLAB = BM * 64;     // BYTES per 32-k slab
  constexpr int BSLAB = BN * 64;
  constexpr int ABUF = 2 * ASLAB;
  constexpr int BBUF = 2 * BSLAB;
  __shared__ unsigned short lds_a[BM * 128];
  __shared__ unsigned short lds_b[BN * 128];
  const int tid = threadIdx.x;
  const int lane = tid & 63;
  const int wave = tid >> 6;
  const int wm = wave >> 1, wn = wave & 1;
  const int quad = lane >> 4, col = lane & 15;

  const int gx = (int)gridDim.x;
  const int nwg = gx * (int)gridDim.y;
  const int bid = (int)blockIdx.y * gx + (int)blockIdx.x;
  const int swz = (bid & 7) * (nwg >> 3) + (bid >> 3);
  const int bx = swz % gx, by = swz / gx;
  const int m0 = (SWAPXY ? bx : by) * BM;
  const int n0 = (SWAPXY ? by : bx) * BN;
  const int kb = (int)blockIdx.z * Ksub;

  floatx4 acc[AF][BF] = {};

  const int srow = tid >> 2;
  const int skoff = (tid & 3) * 8;
  const unsigned short* a_ptr = A + (size_t)(m0 + srow) * K + kb + skoff;
  const unsigned short* b_ptr = BT + (size_t)(n0 + srow) * K + kb + skoff;
  const size_t rowskip = (size_t)64 * K;
  char* const la_dst = (char*)lds_a + tid * 16;
  char* const lb_dst = (char*)lds_b + tid * 16;

  // prologue: stage K-step 0 into buffer 0
#pragma unroll
  for (int h = 0; h < BM / 64; ++h)
#pragma unroll
    for (int s = 0; s < 2; ++s)
      __builtin_amdgcn_global_load_lds((const GLOBAL_AS void*)(a_ptr + h * rowskip + s * 32),
                                       (LDS_AS void*)(la_dst + s * ASLAB + h * 4096), 16, 0, 0);
#pragma unroll
  for (int h = 0; h < BN / 64; ++h)
#pragma unroll
    for (int s = 0; s < 2; ++s)
      __builtin_amdgcn_global_load_lds((const GLOBAL_AS void*)(b_ptr + h * rowskip + s * 32),
                                       (LDS_AS void*)(lb_dst + s * BSLAB + h * 4096), 16, 0, 0);
  a_ptr += 64; b_ptr += 64;
  __syncthreads();

  const int NT = Ksub >> 6;
  int cur = 0;
  for (int t = 0; t < NT; ++t) {
    if (t + 1 < NT) {            // stage next K-step into the other buffer FIRST
      char* la = la_dst + (cur ^ 1) * ABUF;
      char* lb = lb_dst + (cur ^ 1) * BBUF;
#pragma unroll
      for (int h = 0; h < BM / 64; ++h)
#pragma unroll
        for (int s = 0; s < 2; ++s)
          __builtin_amdgcn_global_load_lds((const GLOBAL_AS void*)(a_ptr + h * rowskip + s * 32),
                                           (LDS_AS void*)(la + s * ASLAB + h * 4096), 16, 0, 0);
#pragma unroll
      for (int h = 0; h < BN / 64; ++h)
#pragma unroll
        for (int s = 0; s < 2; ++s)
          __builtin_amdgcn_global_load_lds((const GLOBAL_AS void*)(b_ptr + h * rowskip + s * 32),
                                           (LDS_AS void*)(lb + s * BSLAB + h * 4096), 16, 0, 0);
      a_ptr += 64; b_ptr += 64;
    }
    const char* pa = (const char*)lds_a + cur * ABUF;
    const char* pb = (const char*)lds_b + cur * BBUF;
#pragma unroll
    for (int s = 0; s < 2; ++s) {
      short8 af[AF], bf[BF];
#pragma unroll
      for (int tf = 0; tf < AF; ++tf)
        af[tf] = *(const short8*)(pa + s * ASLAB + (wm * (BM / 2) + tf * 16 + col) * 64 + quad * 16);
#pragma unroll
      for (int tf = 0; tf < BF; ++tf)
        bf[tf] = *(const short8*)(pb + s * BSLAB + (wn * (BN / 2) + tf * 16 + col) * 64 + quad * 16);
#pragma unroll
      for (int tm = 0; tm < AF; ++tm)
#pragma unroll
        for (int tn = 0; tn < BF; ++tn)
          acc[tm][tn] = __builtin_amdgcn_mfma_f32_16x16x32_bf16(af[tm], bf[tn], acc[tm][tn], 0, 0, 0);
    }
    __syncthreads();
    cur ^= 1;
  }

  float* Cfz = Cf + (size_t)blockIdx.z * csplit;
#pragma unroll
  for (int tm = 0; tm < AF; ++tm) {
    const int mg = m0 + wm * (BM / 2) + tm * 16 + quad * 4;
#pragma unroll
    for (int tn = 0; tn < BF; ++tn) {
      const int ng = n0 + wn * (BN / 2) + tn * 16 + col;
#pragma unroll
      for (int r = 0; r < 4; ++r) {
        const float val = acc[tm][tn][r];
        if (WRITE_F32) Cfz[(size_t)(mg + r) * N + ng] = val;
        if (WRITE_BF16) Cb[(size_t)(mg + r) * N + ng] = f2bf_rne(val);
      }
    }
  }
}

// ---------------- GEMM3 (128x64 tile, BK=64, dbuf) fused with scores epilogue -------
__global__ __launch_bounds__(256, 2) void gemm_scores_kernel(
    const unsigned short* __restrict__ A, const unsigned short* __restrict__ BT,
    const float* __restrict__ dec, const float* __restrict__ cov,
    const float* __restrict__ v, float* __restrict__ scores, int M, int N, int K) {
  constexpr int ASLAB = 8192, ABUF = 16384;
  constexpr int BSLAB = 4096, BBUF = 8192;
  __shared__ unsigned short lds_a[128 * 128];
  __shared__ unsigned short lds_b[64 * 128];
  const int tid = threadIdx.x;
  const int lane = tid & 63;
  const int wave = tid >> 6;
  const int wm = wave >> 1, wn = wave & 1;
  const int quad = lane >> 4, col = lane & 15;

  const int gx = (int)gridDim.x;
  const int nwg = gx * (int)gridDim.y;
  const int bid = (int)blockIdx.y * gx + (int)blockIdx.x;
  const int swz = (bid & 7) * (nwg >> 3) + (bid >> 3);
  const int m0 = (swz / gx) * 128, n0 = (swz % gx) * 64;

  floatx4 acc[4][2] = {};

  const int srow = tid >> 2;
  const int skoff = (tid & 3) * 8;
  const unsigned short* a_ptr = A + (size_t)(m0 + srow) * K + skoff;
  const unsigned short* b_ptr = BT + (size_t)(n0 + srow) * K + skoff;
  const size_t rowskip = (size_t)64 * K;
  char* const la_dst = (char*)lds_a + tid * 16;
  char* const lb_dst = (char*)lds_b + tid * 16;

#pragma unroll
  for (int h = 0; h < 2; ++h)
#pragma unroll
    for (int s = 0; s < 2; ++s)
      __builtin_amdgcn_global_load_lds((const GLOBAL_AS void*)(a_ptr + h * rowskip + s * 32),
                                       (LDS_AS void*)(la_dst + s * ASLAB + h * 4096), 16, 0, 0);
#pragma unroll
  for (int s = 0; s < 2; ++s)
    __builtin_amdgcn_global_load_lds((const GLOBAL_AS void*)(b_ptr + s * 32),
                                     (LDS_AS void*)(lb_dst + s * BSLAB), 16, 0, 0);
  a_ptr += 64; b_ptr += 64;
  __syncthreads();

  const int NT = K >> 6;
  int cur = 0;
  for (int t = 0; t < NT; ++t) {
    if (t + 1 < NT) {
      char* la = la_dst + (cur ^ 1) * ABUF;
      char* lb = lb_dst + (cur ^ 1) * BBUF;
#pragma unroll
      for (int h = 0; h < 2; ++h)
#pragma unroll
        for (int s = 0; s < 2; ++s)
          __builtin_amdgcn_global_load_lds((const GLOBAL_AS void*)(a_ptr + h * rowskip + s * 32),
                                           (LDS_AS void*)(la + s * ASLAB + h * 4096), 16, 0, 0);
#pragma unroll
      for (int s = 0; s < 2; ++s)
        __builtin_amdgcn_global_load_lds((const GLOBAL_AS void*)(b_ptr + s * 32),
                                         (LDS_AS void*)(lb + s * BSLAB), 16, 0, 0);
      a_ptr += 64; b_ptr += 64;
    }
    const char* pa = (const char*)lds_a + cur * ABUF;
    const char* pb = (const char*)lds_b + cur * BBUF;
#pragma unroll
    for (int s = 0; s < 2; ++s) {
      short8 af[4], bf[2];
#pragma unroll
      for (int tf = 0; tf < 4; ++tf)
        af[tf] = *(const short8*)(pa + s * ASLAB + (wm * 64 + tf * 16 + col) * 64 + quad * 16);
#pragma unroll
      for (int tf = 0; tf < 2; ++tf)
        bf[tf] = *(const short8*)(pb + s * BSLAB + (wn * 32 + tf * 16 + col) * 64 + quad * 16);
#pragma unroll
      for (int tm = 0; tm < 4; ++tm)
#pragma unroll
        for (int tn = 0; tn < 2; ++tn)
          acc[tm][tn] = __builtin_amdgcn_mfma_f32_16x16x32_bf16(af[tm], bf[tn], acc[tm][tn], 0, 0, 0);
    }
    __syncthreads();
    cur ^= 1;
  }

  const int n_base = n0 + wn * 32;
  float vv[2];
#pragma unroll
  for (int tn = 0; tn < 2; ++tn) vv[tn] = v[n_base + tn * 16 + col];
#pragma unroll
  for (int tm = 0; tm < 4; ++tm) {
#pragma unroll
    for (int r = 0; r < 4; ++r) {
      const int row = m0 + wm * 64 + tm * 16 + quad * 4 + r;
      const int b = row / 196;
      const float cw = cov[row];
      const float* dr = dec + b * 1024 + n_base;
      float s = 0.f;
#pragma unroll
      for (int tn = 0; tn < 2; ++tn)
        s += tanhf(acc[tm][tn][r] + dr[tn * 16 + col] + cw) * vv[tn];
      s += __shfl_xor(s, 1, 64);
      s += __shfl_xor(s, 2, 64);
      s += __shfl_xor(s, 4, 64);
      s += __shfl_xor(s, 8, 64);
      if ((lane & 15) == 0) atomicAdd(&scores[row], s);
    }
  }
}

// ---------------- softmax over 196 regions: alpha + coverage outputs ----------------
__global__ void softmax_kernel(const float* __restrict__ scores, const float* __restrict__ cov,
                               float* __restrict__ alpha_ws, float* __restrict__ out) {
  const int b = blockIdx.x, tid = threadIdx.x;
  const int lane = tid & 63, wid = tid >> 6;
  __shared__ float red[8];
  float s = (tid < 196) ? scores[b * 196 + tid] : -1e30f;
  float m = s;
  for (int off = 32; off > 0; off >>= 1) m = fmaxf(m, __shfl_xor(m, off, 64));
  if (lane == 0) red[wid] = m;
  __syncthreads();
  m = fmaxf(fmaxf(red[0], red[1]), fmaxf(red[2], red[3]));
  float e = (tid < 196) ? __expf(s - m) : 0.f;
  float t = e;
  for (int off = 32; off > 0; off >>= 1) t += __shfl_xor(t, off, 64);
  if (lane == 0) red[4 + wid] = t;
  __syncthreads();
  const float tot = red[4] + red[5] + red[6] + red[7];
  const float a = e / tot;
  if (tid < 196) {
    alpha_ws[b * 196 + tid] = a;
    out[32768 + b * 196 + tid] = cov[b * 196 + tid] + a;   // coverage_new
    out[32768 + 6272 + b * 196 + tid] = a;                 // alpha_a
  }
}

// ---------------- context: c_img[b, :] = sum_t alpha[b,t] * gstar[b,t,:] ------------
__global__ __launch_bounds__(256) void ctx_kernel(const float* __restrict__ alpha,
                                                  const float* __restrict__ gstar,
                                                  float* __restrict__ out) {
  const int b = blockIdx.y;
  const int colbase = blockIdx.x * 128;
  const int c = threadIdx.x & 127;
  const int half = threadIdx.x >> 7;
  const float* g = gstar + ((size_t)b * 196 + half * 98) * 1024 + colbase + c;
  const float* al = alpha + b * 196 + half * 98;
  float acc = 0.f;
#pragma unroll 7
  for (int t = 0; t < 98; ++t) acc += al[t] * g[(size_t)t * 1024];
  __shared__ float part[256];
  part[threadIdx.x] = acc;
  __syncthreads();
  if (threadIdx.x < 128)
    out[b * 1024 + colbase + threadIdx.x] = part[threadIdx.x] + part[threadIdx.x + 128];
}

// ---------------- launch ----------------
extern "C" void kernel_launch(void* const* d_in, const int* in_sizes, int n_in,
                              void* d_out, int out_size, void* d_ws, size_t ws_size,
                              hipStream_t stream) {
  (void)in_sizes; (void)n_in; (void)out_size; (void)ws_size;
  const float* gf   = (const float*)d_in[0];   // [6272, 4096]
  const float* sth  = (const float*)d_in[1];   // [32, 1024]
  const float* cov  = (const float*)d_in[2];   // [6272]
  const float* Wg   = (const float*)d_in[3];   // [4096, 4096]
  const float* bg   = (const float*)d_in[4];   // [4096]
  const float* Gs   = (const float*)d_in[5];   // [4096, 1024]
  const float* bgs  = (const float*)d_in[6];   // [1024]
  const float* Wgs  = (const float*)d_in[7];   // [1024, 1024]
  const float* Wdec = (const float*)d_in[8];   // [1024, 1024]
  const float* bdec = (const float*)d_in[9];   // [1024]
  const float* v    = (const float*)d_in[10];  // [1024]
  float* out = (float*)d_out;

  char* ws = (char*)d_ws;
  // Memory map (lifetimes):
  //   [0, 51.38M)          gf_bf16 [prep1 -> GEMM2]; then gstar_bf16 [reduce2 -> GEMM3]
  //   [51.38M, 84.93M)     Wg_bf16 [prep1 -> GEMM1]
  //   [51.38M, 77.07M)     p0 f32 partial [GEMM2 -> reduce2]; then gstar_f32 (in place) [-> ctx]
  //   [77.07M, 102.76M)    p1 f32 partial [GEMM2 -> reduce2]
  //   [84.93M, 93.32M)     GsT_bf16 [prep1 -> GEMM1]   (overlaps p1; disjoint lifetimes)
  //   [102.76M, 111.15M)   C1T_bf16 [GEMM1 -> GEMM2]
  //   [111.15M, 113.25M)   WgsT_bf16 [prep2 -> GEMM3]
  //   [113.25M+)           bias1, dec, scores, alpha (small)
  unsigned short* gf_bf   = (unsigned short*)(ws + 0);
  unsigned short* gstar_b = (unsigned short*)(ws + 0);
  unsigned short* Wg_bf   = (unsigned short*)(ws + 51380224);
  float*          p0      = (float*)(ws + 51380224);
  float*          gstar_f = (float*)(ws + 51380224);
  float*          p1      = (float*)(ws + 77070336);
  unsigned short* GsT     = (unsigned short*)(ws + 84934656);
  unsigned short* C1T_b   = (unsigned short*)(ws + 102760448);
  unsigned short* WgsT    = (unsigned short*)(ws + 111149056);
  float*          bias1   = (float*)(ws + 113246208);
  float*          dec     = (float*)(ws + 113262592);
  float*          scores  = (float*)(ws + 113393664);
  float*          alpha   = (float*)(ws + 113426432);

  // 1. bias1 init (bgs) + fused prep1: cast gf, cast Wg, transpose Gs, bias1 += bg@Gs
  hipMemcpyAsync(bias1, bgs, 4096, hipMemcpyDeviceToDevice, stream);
  prep1_kernel<<<24896, 256, 0, stream>>>(gf, gf_bf, Wg, Wg_bf, Gs, GsT, bg, bias1);
  // 2. GEMM1: C1T[1024,4096] = GsT @ Wg^T, bf16 out. 128x64, SWAPXY, 512 blocks.
  gemm_tile_kernel<128, 64, false, true, true><<<dim3(8, 64, 1), 256, 0, stream>>>(
      GsT, Wg_bf, nullptr, C1T_b, 1024, 4096, 4096, 4096, 0);
  // 3. fused prep2: transpose Wgs, dec = sth@Wdec + bdec, zero scores
  prep2_kernel<<<1047, 256, 0, stream>>>(Wgs, WgsT, sth, Wdec, bdec, dec, scores);
  // 4. GEMM2 split-K x2: p[z][6272,1024] = gf @ C1 (K-half z). 128x128, 784 blocks.
  gemm_tile_kernel<128, 128, true, false, false><<<dim3(8, 49, 2), 256, 0, stream>>>(
      gf_bf, C1T_b, p0, nullptr, 6272, 1024, 4096, 2048, 6422528);
  // 5. reduce: gstar = p0 + p1 + bias1 (f32 in-place at p0, bf16 at ws+0)
  reduce2_kernel<<<6272, 256, 0, stream>>>(p0, p1, bias1, gstar_f, gstar_b);
  // 6. GEMM3 fused with scores epilogue (w_g_star never materialized). 784 blocks.
  gemm_scores_kernel<<<dim3(16, 49), 256, 0, stream>>>(
      gstar_b, WgsT, dec, cov, v, scores, 6272, 1024, 1024);
  // 7. softmax (alpha + coverage outputs), then parallel context
  softmax_kernel<<<32, 256, 0, stream>>>(scores, cov, alpha, out);
  ctx_kernel<<<dim3(8, 32), 256, 0, stream>>>(alpha, gstar_f, out);
}

// Round 5
// 518.496 us; speedup vs baseline: 1.3185x; 1.3185x over previous
//
#include <hip/hip_runtime.h>
#include <hip/hip_bf16.h>

typedef __attribute__((ext_vector_type(8))) short short8;
typedef __attribute__((ext_vector_type(4))) short short4v;
typedef __attribute__((ext_vector_type(4))) float floatx4;

#define GLOBAL_AS __attribute__((address_space(1)))
#define LDS_AS    __attribute__((address_space(3)))

__device__ __forceinline__ unsigned short f2bf_rne(float x) {
  unsigned int u = __float_as_uint(x);
  u += 0x7fffu + ((u >> 16) & 1u);
  return (unsigned short)(u >> 16);
}

// ---------------- device helpers for fused prep kernel ----------------
__device__ __forceinline__ void cast8_body(const float* __restrict__ in,
                                           unsigned short* __restrict__ out,
                                           int blk, int n8) {
  int i = blk * 256 + threadIdx.x;
  if (i >= n8) return;
  const float4* p = (const float4*)in;
  float4 v0 = p[2 * i], v1 = p[2 * i + 1];
  short8 o;
  o[0] = (short)f2bf_rne(v0.x); o[1] = (short)f2bf_rne(v0.y);
  o[2] = (short)f2bf_rne(v0.z); o[3] = (short)f2bf_rne(v0.w);
  o[4] = (short)f2bf_rne(v1.x); o[5] = (short)f2bf_rne(v1.y);
  o[6] = (short)f2bf_rne(v1.z); o[7] = (short)f2bf_rne(v1.w);
  *(short8*)(out + 8 * (size_t)i) = o;
}

__device__ __forceinline__ void trans32_body(const float* __restrict__ in,
                                             unsigned short* __restrict__ out,
                                             int R, int C, int bx, int by) {
  __shared__ unsigned short tile[32][33];
  int tx = threadIdx.x & 31, ty = threadIdx.x >> 5;
  int r0 = by * 32, c0 = bx * 32;
#pragma unroll
  for (int j = 0; j < 32; j += 8)
    tile[ty + j][tx] = f2bf_rne(in[(size_t)(r0 + ty + j) * C + c0 + tx]);
  __syncthreads();
#pragma unroll
  for (int j = 0; j < 32; j += 8)
    out[(size_t)(c0 + ty + j) * R + r0 + tx] = tile[tx][ty + j];
}

// ---------------- prep1: cast gf, cast Wg, transpose Gs, bias1 accum, transpose Wgs,
//                  init dec = bdec broadcast, zero scores ----------------------------
// bias1 must be pre-initialized to bgs via hipMemcpyAsync before this launch.
// dec_accum_kernel (separate launch) adds sth @ Wdec on top of the init written here.
__global__ void prep1_kernel(const float* __restrict__ gf, unsigned short* __restrict__ gf_bf,
                             const float* __restrict__ Wg, unsigned short* __restrict__ Wg_bf,
                             const float* __restrict__ Gs, unsigned short* __restrict__ GsT,
                             const float* __restrict__ bg, float* __restrict__ bias1,
                             const float* __restrict__ Wgs, unsigned short* __restrict__ WgsT,
                             const float* __restrict__ bdec, float* __restrict__ dec,
                             float* __restrict__ scores) {
  const int b = blockIdx.x;
  if (b < 12544) {
    cast8_body(gf, gf_bf, b, 3211264);
  } else if (b < 20736) {
    cast8_body(Wg, Wg_bf, b - 12544, 2097152);
  } else if (b < 24832) {
    int bb = b - 20736;                       // 4096 blocks: 32 col-tiles x 128 row-tiles
    trans32_body(Gs, GsT, 4096, 1024, bb & 31, bb >> 5);
  } else if (b < 24896) {
    int bb = b - 24832;                       // 64 blocks: 4 j-chunks x 16 k-chunks
    int j = (bb & 3) * 256 + threadIdx.x;
    int k0 = (bb >> 2) * 256;
    float acc = 0.f;
    for (int k = 0; k < 256; ++k) acc += bg[k0 + k] * Gs[(size_t)(k0 + k) * 1024 + j];
    atomicAdd(&bias1[j], acc);
  } else if (b < 25920) {
    int bb = b - 24896;                       // 1024 blocks: Wgs transpose
    trans32_body(Wgs, WgsT, 1024, 1024, bb & 31, bb >> 5);
  } else if (b < 26048) {
    int i = (b - 25920) * 256 + threadIdx.x;  // 128 blocks: dec init (32x1024)
    dec[i] = bdec[i & 1023];
  } else {
    int i = (b - 26048) * 256 + threadIdx.x;  // 7 blocks zero 1568 float4 = 6272 floats
    if (i < 1568) ((float4*)scores)[i] = make_float4(0.f, 0.f, 0.f, 0.f);
  }
}

// ---------------- dec += s_t_hat @ Wdec (k-split, LDS-staged, proven structure) -----
__global__ void dec_accum_kernel(const float* __restrict__ sth, const float* __restrict__ Wdec,
                                 float* __restrict__ dec) {
  __shared__ float ss[32][128];
  const int tid = threadIdx.x;
  const int k0 = blockIdx.y * 128;
  for (int i = tid; i < 32 * 128; i += 256) {
    int bb = i >> 7, kk = i & 127;
    ss[bb][kk] = sth[bb * 1024 + k0 + kk];
  }
  __syncthreads();
  const int j = blockIdx.x * 256 + tid;
  float acc[32];
#pragma unroll
  for (int b = 0; b < 32; ++b) acc[b] = 0.f;
  for (int kk = 0; kk < 128; ++kk) {
    float w = Wdec[(size_t)(k0 + kk) * 1024 + j];
#pragma unroll
    for (int b = 0; b < 32; ++b) acc[b] += ss[b][kk] * w;
  }
  for (int b = 0; b < 32; ++b) atomicAdd(&dec[b * 1024 + j], acc[b]);
}

// ---------------- split-K reduce: gstar = p0 + p1 + bias1 (f32 in-place + bf16) -----
__global__ __launch_bounds__(256) void reduce2_kernel(const float* __restrict__ p0,
                                                      const float* __restrict__ p1,
                                                      const float* __restrict__ bias,
                                                      float* __restrict__ gf32,
                                                      unsigned short* __restrict__ gb16) {
  const int i = blockIdx.x * 256 + threadIdx.x;     // 6272 blocks -> i < 1,605,632
  float4 a = ((const float4*)p0)[i];
  float4 b = ((const float4*)p1)[i];
  float4 bv = ((const float4*)bias)[i & 255];       // row stride 1024 floats = 256 float4
  float4 r;
  r.x = a.x + b.x + bv.x; r.y = a.y + b.y + bv.y;
  r.z = a.z + b.z + bv.z; r.w = a.w + b.w + bv.w;
  ((float4*)gf32)[i] = r;                           // in-place over p0 (same thread)
  short4v o;
  o[0] = (short)f2bf_rne(r.x); o[1] = (short)f2bf_rne(r.y);
  o[2] = (short)f2bf_rne(r.z); o[3] = (short)f2bf_rne(r.w);
  *(short4v*)(gb16 + 4 * (size_t)i) = o;
}

// ---------------- tiled GEMM, BK=64, double-buffered LDS: C = A @ BT^T --------------
// 2-phase drain dbuf (round-2 proven). Split-K via blockIdx.z: each z-plane covers
// Ksub of K, writing f32 partials to Cf + z*csplit (GEMM2) or bf16 direct (GEMM1).
// XCD-chunked swizzle per z-plane; SWAPXY: chunk axis follows the larger operand.
template <int BM, int BN, bool WRITE_F32, bool WRITE_BF16, bool SWAPXY>
__global__ __launch_bounds__(256, 2) void gemm_tile_kernel(
    const unsigned short* __restrict__ A, const unsigned short* __restrict__ BT,
    float* __restrict__ Cf, unsigned short* __restrict__ Cb,
    int M, int N, int K, int Ksub, size_t csplit) {
  constexpr int AF = BM / 32;
  constexpr int BF = BN / 32;
  constexpr int ASLAB = BM * 64;     // BYTES per 32-k slab
  constexpr int BSLAB = BN * 64;
  constexpr int ABUF = 2 * ASLAB;
  constexpr int BBUF = 2 * BSLAB;
  __shared__ unsigned short lds_a[BM * 128];
  __shared__ unsigned short lds_b[BN * 128];
  const int tid = threadIdx.x;
  const int lane = tid & 63;
  const int wave = tid >> 6;
  const int wm = wave >> 1, wn = wave & 1;
  const int quad = lane >> 4, col = lane & 15;

  const int gx = (int)gridDim.x;
  const int nwg = gx * (int)gridDim.y;
  const int bid = (int)blockIdx.y * gx + (int)blockIdx.x;
  const int swz = (bid & 7) * (nwg >> 3) + (bid >> 3);
  const int bx = swz % gx, by = swz / gx;
  const int m0 = (SWAPXY ? bx : by) * BM;
  const int n0 = (SWAPXY ? by : bx) * BN;
  const int kb = (int)blockIdx.z * Ksub;

  floatx4 acc[AF][BF] = {};

  const int srow = tid >> 2;
  const int skoff = (tid & 3) * 8;
  const unsigned short* a_ptr = A + (size_t)(m0 + srow) * K + kb + skoff;
  const unsigned short* b_ptr = BT + (size_t)(n0 + srow) * K + kb + skoff;
  const size_t rowskip = (size_t)64 * K;
  char* const la_dst = (char*)lds_a + tid * 16;
  char* const lb_dst = (char*)lds_b + tid * 16;

  // prologue: stage K-step 0 into buffer 0
#pragma unroll
  for (int h = 0; h < BM / 64; ++h)
#pragma unroll
    for (int s = 0; s < 2; ++s)
      __builtin_amdgcn_global_load_lds((const GLOBAL_AS void*)(a_ptr + h * rowskip + s * 32),
                                       (LDS_AS void*)(la_dst + s * ASLAB + h * 4096), 16, 0, 0);
#pragma unroll
  for (int h = 0; h < BN / 64; ++h)
#pragma unroll
    for (int s = 0; s < 2; ++s)
      __builtin_amdgcn_global_load_lds((const GLOBAL_AS void*)(b_ptr + h * rowskip + s * 32),
                                       (LDS_AS void*)(lb_dst + s * BSLAB + h * 4096), 16, 0, 0);
  a_ptr += 64; b_ptr += 64;
  __syncthreads();

  const int NT = Ksub >> 6;
  int cur = 0;
  for (int t = 0; t < NT; ++t) {
    if (t + 1 < NT) {            // stage next K-step into the other buffer FIRST
      char* la = la_dst + (cur ^ 1) * ABUF;
      char* lb = lb_dst + (cur ^ 1) * BBUF;
#pragma unroll
      for (int h = 0; h < BM / 64; ++h)
#pragma unroll
        for (int s = 0; s < 2; ++s)
          __builtin_amdgcn_global_load_lds((const GLOBAL_AS void*)(a_ptr + h * rowskip + s * 32),
                                           (LDS_AS void*)(la + s * ASLAB + h * 4096), 16, 0, 0);
#pragma unroll
      for (int h = 0; h < BN / 64; ++h)
#pragma unroll
        for (int s = 0; s < 2; ++s)
          __builtin_amdgcn_global_load_lds((const GLOBAL_AS void*)(b_ptr + h * rowskip + s * 32),
                                           (LDS_AS void*)(lb + s * BSLAB + h * 4096), 16, 0, 0);
      a_ptr += 64; b_ptr += 64;
    }
    const char* pa = (const char*)lds_a + cur * ABUF;
    const char* pb = (const char*)lds_b + cur * BBUF;
#pragma unroll
    for (int s = 0; s < 2; ++s) {
      short8 af[AF], bf[BF];
#pragma unroll
      for (int tf = 0; tf < AF; ++tf)
        af[tf] = *(const short8*)(pa + s * ASLAB + (wm * (BM / 2) + tf * 16 + col) * 64 + quad * 16);
#pragma unroll
      for (int tf = 0; tf < BF; ++tf)
        bf[tf] = *(const short8*)(pb + s * BSLAB + (wn * (BN / 2) + tf * 16 + col) * 64 + quad * 16);
#pragma unroll
      for (int tm = 0; tm < AF; ++tm)
#pragma unroll
        for (int tn = 0; tn < BF; ++tn)
          acc[tm][tn] = __builtin_amdgcn_mfma_f32_16x16x32_bf16(af[tm], bf[tn], acc[tm][tn], 0, 0, 0);
    }
    __syncthreads();
    cur ^= 1;
  }

  float* Cfz = Cf + (size_t)blockIdx.z * csplit;
#pragma unroll
  for (int tm = 0; tm < AF; ++tm) {
    const int mg = m0 + wm * (BM / 2) + tm * 16 + quad * 4;
#pragma unroll
    for (int tn = 0; tn < BF; ++tn) {
      const int ng = n0 + wn * (BN / 2) + tn * 16 + col;
#pragma unroll
      for (int r = 0; r < 4; ++r) {
        const float val = acc[tm][tn][r];
        if (WRITE_F32) Cfz[(size_t)(mg + r) * N + ng] = val;
        if (WRITE_BF16) Cb[(size_t)(mg + r) * N + ng] = f2bf_rne(val);
      }
    }
  }
}

// ---------------- GEMM3 (128x64 tile, BK=64, dbuf) fused with scores epilogue -------
__global__ __launch_bounds__(256, 2) void gemm_scores_kernel(
    const unsigned short* __restrict__ A, const unsigned short* __restrict__ BT,
    const float* __restrict__ dec, const float* __restrict__ cov,
    const float* __restrict__ v, float* __restrict__ scores, int M, int N, int K) {
  constexpr int ASLAB = 8192, ABUF = 16384;
  constexpr int BSLAB = 4096, BBUF = 8192;
  __shared__ unsigned short lds_a[128 * 128];
  __shared__ unsigned short lds_b[64 * 128];
  const int tid = threadIdx.x;
  const int lane = tid & 63;
  const int wave = tid >> 6;
  const int wm = wave >> 1, wn = wave & 1;
  const int quad = lane >> 4, col = lane & 15;

  const int gx = (int)gridDim.x;
  const int nwg = gx * (int)gridDim.y;
  const int bid = (int)blockIdx.y * gx + (int)blockIdx.x;
  const int swz = (bid & 7) * (nwg >> 3) + (bid >> 3);
  const int m0 = (swz / gx) * 128, n0 = (swz % gx) * 64;

  floatx4 acc[4][2] = {};

  const int srow = tid >> 2;
  const int skoff = (tid & 3) * 8;
  const unsigned short* a_ptr = A + (size_t)(m0 + srow) * K + skoff;
  const unsigned short* b_ptr = BT + (size_t)(n0 + srow) * K + skoff;
  const size_t rowskip = (size_t)64 * K;
  char* const la_dst = (char*)lds_a + tid * 16;
  char* const lb_dst = (char*)lds_b + tid * 16;

#pragma unroll
  for (int h = 0; h < 2; ++h)
#pragma unroll
    for (int s = 0; s < 2; ++s)
      __builtin_amdgcn_global_load_lds((const GLOBAL_AS void*)(a_ptr + h * rowskip + s * 32),
                                       (LDS_AS void*)(la_dst + s * ASLAB + h * 4096), 16, 0, 0);
#pragma unroll
  for (int s = 0; s < 2; ++s)
    __builtin_amdgcn_global_load_lds((const GLOBAL_AS void*)(b_ptr + s * 32),
                                     (LDS_AS void*)(lb_dst + s * BSLAB), 16, 0, 0);
  a_ptr += 64; b_ptr += 64;
  __syncthreads();

  const int NT = K >> 6;
  int cur = 0;
  for (int t = 0; t < NT; ++t) {
    if (t + 1 < NT) {
      char* la = la_dst + (cur ^ 1) * ABUF;
      char* lb = lb_dst + (cur ^ 1) * BBUF;
#pragma unroll
      for (int h = 0; h < 2; ++h)
#pragma unroll
        for (int s = 0; s < 2; ++s)
          __builtin_amdgcn_global_load_lds((const GLOBAL_AS void*)(a_ptr + h * rowskip + s * 32),
                                           (LDS_AS void*)(la + s * ASLAB + h * 4096), 16, 0, 0);
#pragma unroll
      for (int s = 0; s < 2; ++s)
        __builtin_amdgcn_global_load_lds((const GLOBAL_AS void*)(b_ptr + s * 32),
                                         (LDS_AS void*)(lb + s * BSLAB), 16, 0, 0);
      a_ptr += 64; b_ptr += 64;
    }
    const char* pa = (const char*)lds_a + cur * ABUF;
    const char* pb = (const char*)lds_b + cur * BBUF;
#pragma unroll
    for (int s = 0; s < 2; ++s) {
      short8 af[4], bf[2];
#pragma unroll
      for (int tf = 0; tf < 4; ++tf)
        af[tf] = *(const short8*)(pa + s * ASLAB + (wm * 64 + tf * 16 + col) * 64 + quad * 16);
#pragma unroll
      for (int tf = 0; tf < 2; ++tf)
        bf[tf] = *(const short8*)(pb + s * BSLAB + (wn * 32 + tf * 16 + col) * 64 + quad * 16);
#pragma unroll
      for (int tm = 0; tm < 4; ++tm)
#pragma unroll
        for (int tn = 0; tn < 2; ++tn)
          acc[tm][tn] = __builtin_amdgcn_mfma_f32_16x16x32_bf16(af[tm], bf[tn], acc[tm][tn], 0, 0, 0);
    }
    __syncthreads();
    cur ^= 1;
  }

  const int n_base = n0 + wn * 32;
  float vv[2];
#pragma unroll
  for (int tn = 0; tn < 2; ++tn) vv[tn] = v[n_base + tn * 16 + col];
#pragma unroll
  for (int tm = 0; tm < 4; ++tm) {
#pragma unroll
    for (int r = 0; r < 4; ++r) {
      const int row = m0 + wm * 64 + tm * 16 + quad * 4 + r;
      const int b = row / 196;
      const float cw = cov[row];
      const float* dr = dec + b * 1024 + n_base;
      float s = 0.f;
#pragma unroll
      for (int tn = 0; tn < 2; ++tn)
        s += tanhf(acc[tm][tn][r] + dr[tn * 16 + col] + cw) * vv[tn];
      s += __shfl_xor(s, 1, 64);
      s += __shfl_xor(s, 2, 64);
      s += __shfl_xor(s, 4, 64);
      s += __shfl_xor(s, 8, 64);
      if ((lane & 15) == 0) atomicAdd(&scores[row], s);
    }
  }
}

// ---------------- softmax over 196 regions: alpha + coverage outputs ----------------
__global__ void softmax_kernel(const float* __restrict__ scores, const float* __restrict__ cov,
                               float* __restrict__ alpha_ws, float* __restrict__ out) {
  const int b = blockIdx.x, tid = threadIdx.x;
  const int lane = tid & 63, wid = tid >> 6;
  __shared__ float red[8];
  float s = (tid < 196) ? scores[b * 196 + tid] : -1e30f;
  float m = s;
  for (int off = 32; off > 0; off >>= 1) m = fmaxf(m, __shfl_xor(m, off, 64));
  if (lane == 0) red[wid] = m;
  __syncthreads();
  m = fmaxf(fmaxf(red[0], red[1]), fmaxf(red[2], red[3]));
  float e = (tid < 196) ? __expf(s - m) : 0.f;
  float t = e;
  for (int off = 32; off > 0; off >>= 1) t += __shfl_xor(t, off, 64);
  if (lane == 0) red[4 + wid] = t;
  __syncthreads();
  const float tot = red[4] + red[5] + red[6] + red[7];
  const float a = e / tot;
  if (tid < 196) {
    alpha_ws[b * 196 + tid] = a;
    out[32768 + b * 196 + tid] = cov[b * 196 + tid] + a;   // coverage_new
    out[32768 + 6272 + b * 196 + tid] = a;                 // alpha_a
  }
}

// ---------------- context: c_img[b, :] = sum_t alpha[b,t] * gstar[b,t,:] ------------
__global__ __launch_bounds__(256) void ctx_kernel(const float* __restrict__ alpha,
                                                  const float* __restrict__ gstar,
                                                  float* __restrict__ out) {
  const int b = blockIdx.y;
  const int colbase = blockIdx.x * 128;
  const int c = threadIdx.x & 127;
  const int half = threadIdx.x >> 7;
  const float* g = gstar + ((size_t)b * 196 + half * 98) * 1024 + colbase + c;
  const float* al = alpha + b * 196 + half * 98;
  float acc = 0.f;
#pragma unroll 7
  for (int t = 0; t < 98; ++t) acc += al[t] * g[(size_t)t * 1024];
  __shared__ float part[256];
  part[threadIdx.x] = acc;
  __syncthreads();
  if (threadIdx.x < 128)
    out[b * 1024 + colbase + threadIdx.x] = part[threadIdx.x] + part[threadIdx.x + 128];
}

// ---------------- launch ----------------
extern "C" void kernel_launch(void* const* d_in, const int* in_sizes, int n_in,
                              void* d_out, int out_size, void* d_ws, size_t ws_size,
                              hipStream_t stream) {
  (void)in_sizes; (void)n_in; (void)out_size; (void)ws_size;
  const float* gf   = (const float*)d_in[0];   // [6272, 4096]
  const float* sth  = (const float*)d_in[1];   // [32, 1024]
  const float* cov  = (const float*)d_in[2];   // [6272]
  const float* Wg   = (const float*)d_in[3];   // [4096, 4096]
  const float* bg   = (const float*)d_in[4];   // [4096]
  const float* Gs   = (const float*)d_in[5];   // [4096, 1024]
  const float* bgs  = (const float*)d_in[6];   // [1024]
  const float* Wgs  = (const float*)d_in[7];   // [1024, 1024]
  const float* Wdec = (const float*)d_in[8];   // [1024, 1024]
  const float* bdec = (const float*)d_in[9];   // [1024]
  const float* v    = (const float*)d_in[10];  // [1024]
  float* out = (float*)d_out;

  char* ws = (char*)d_ws;
  // Memory map (lifetimes):
  //   [0, 51.38M)          gf_bf16 [prep1 -> GEMM2]; then gstar_bf16 [reduce2 -> GEMM3]
  //   [51.38M, 84.93M)     Wg_bf16 [prep1 -> GEMM1]
  //   [51.38M, 77.07M)     p0 f32 partial [GEMM2 -> reduce2]; then gstar_f32 (in place) [-> ctx]
  //   [77.07M, 102.76M)    p1 f32 partial [GEMM2 -> reduce2]
  //   [84.93M, 93.32M)     GsT_bf16 [prep1 -> GEMM1]   (overlaps p1; disjoint lifetimes)
  //   [102.76M, 111.15M)   C1T_bf16 [GEMM1 -> GEMM2]
  //   [111.15M, 113.25M)   WgsT_bf16 [prep1 -> GEMM3]
  //   [113.25M+)           bias1, dec, scores, alpha (small)
  unsigned short* gf_bf   = (unsigned short*)(ws + 0);
  unsigned short* gstar_b = (unsigned short*)(ws + 0);
  unsigned short* Wg_bf   = (unsigned short*)(ws + 51380224);
  float*          p0      = (float*)(ws + 51380224);
  float*          gstar_f = (float*)(ws + 51380224);
  float*          p1      = (float*)(ws + 77070336);
  unsigned short* GsT     = (unsigned short*)(ws + 84934656);
  unsigned short* C1T_b   = (unsigned short*)(ws + 102760448);
  unsigned short* WgsT    = (unsigned short*)(ws + 111149056);
  float*          bias1   = (float*)(ws + 113246208);
  float*          dec     = (float*)(ws + 113262592);
  float*          scores  = (float*)(ws + 113393664);
  float*          alpha   = (float*)(ws + 113426432);

  // 1. bias1 init (bgs) + fused prep1: casts, transposes, bias1 accum, dec init, zero
  hipMemcpyAsync(bias1, bgs, 4096, hipMemcpyDeviceToDevice, stream);
  prep1_kernel<<<26055, 256, 0, stream>>>(gf, gf_bf, Wg, Wg_bf, Gs, GsT, bg, bias1,
                                          Wgs, WgsT, bdec, dec, scores);
  // 2. dec += sth @ Wdec (k-split x8, LDS-staged, 32 blocks — proven structure)
  dec_accum_kernel<<<dim3(4, 8), 256, 0, stream>>>(sth, Wdec, dec);
  // 3. GEMM1: C1T[1024,4096] = GsT @ Wg^T, bf16 out. 128x64, SWAPXY, 512 blocks.
  gemm_tile_kernel<128, 64, false, true, true><<<dim3(8, 64, 1), 256, 0, stream>>>(
      GsT, Wg_bf, nullptr, C1T_b, 1024, 4096, 4096, 4096, 0);
  // 4. GEMM2 split-K x2: p[z][6272,1024] = gf @ C1 (K-half z). 128x128, 784 blocks.
  gemm_tile_kernel<128, 128, true, false, false><<<dim3(8, 49, 2), 256, 0, stream>>>(
      gf_bf, C1T_b, p0, nullptr, 6272, 1024, 4096, 2048, 6422528);
  // 5. reduce: gstar = p0 + p1 + bias1 (f32 in-place at p0, bf16 at ws+0)
  reduce2_kernel<<<6272, 256, 0, stream>>>(p0, p1, bias1, gstar_f, gstar_b);
  // 6. GEMM3 fused with scores epilogue (w_g_star never materialized). 784 blocks.
  gemm_scores_kernel<<<dim3(16, 49), 256, 0, stream>>>(
      gstar_b, WgsT, dec, cov, v, scores, 6272, 1024, 1024);
  // 7. softmax (alpha + coverage outputs), then parallel context
  softmax_kernel<<<32, 256, 0, stream>>>(scores, cov, alpha, out);
  ctx_kernel<<<dim3(8, 32), 256, 0, stream>>>(alpha, gstar_f, out);
}

// Round 6
// 487.129 us; speedup vs baseline: 1.4034x; 1.0644x over previous
//
#include <hip/hip_runtime.h>
#include <hip/hip_bf16.h>

typedef __attribute__((ext_vector_type(8))) short short8;
typedef __attribute__((ext_vector_type(4))) float floatx4;

#define GLOBAL_AS __attribute__((address_space(1)))
#define LDS_AS    __attribute__((address_space(3)))

__device__ __forceinline__ unsigned short f2bf_rne(float x) {
  unsigned int u = __float_as_uint(x);
  u += 0x7fffu + ((u >> 16) & 1u);
  return (unsigned short)(u >> 16);
}

// ---------------- device helpers for fused prep kernel ----------------
__device__ __forceinline__ void cast8_body(const float* __restrict__ in,
                                           unsigned short* __restrict__ out,
                                           int blk, int n8) {
  int i = blk * 256 + threadIdx.x;
  if (i >= n8) return;
  const float4* p = (const float4*)in;
  float4 v0 = p[2 * i], v1 = p[2 * i + 1];
  short8 o;
  o[0] = (short)f2bf_rne(v0.x); o[1] = (short)f2bf_rne(v0.y);
  o[2] = (short)f2bf_rne(v0.z); o[3] = (short)f2bf_rne(v0.w);
  o[4] = (short)f2bf_rne(v1.x); o[5] = (short)f2bf_rne(v1.y);
  o[6] = (short)f2bf_rne(v1.z); o[7] = (short)f2bf_rne(v1.w);
  *(short8*)(out + 8 * (size_t)i) = o;
}

__device__ __forceinline__ void trans32_body(const float* __restrict__ in,
                                             unsigned short* __restrict__ out,
                                             int R, int C, int bx, int by) {
  __shared__ unsigned short tile[32][33];
  int tx = threadIdx.x & 31, ty = threadIdx.x >> 5;
  int r0 = by * 32, c0 = bx * 32;
#pragma unroll
  for (int j = 0; j < 32; j += 8)
    tile[ty + j][tx] = f2bf_rne(in[(size_t)(r0 + ty + j) * C + c0 + tx]);
  __syncthreads();
#pragma unroll
  for (int j = 0; j < 32; j += 8)
    out[(size_t)(c0 + ty + j) * R + r0 + tx] = tile[tx][ty + j];
}

// ---------------- prep1: cast gf, cast Wg, transpose Gs, bias1 accum, transpose Wgs,
//                  init dec = bdec broadcast, zero scores ----------------------------
// bias1 must be pre-initialized to bgs via hipMemcpyAsync before this launch.
// dec_accum_kernel (separate launch) adds sth @ Wdec on top of the init written here.
__global__ void prep1_kernel(const float* __restrict__ gf, unsigned short* __restrict__ gf_bf,
                             const float* __restrict__ Wg, unsigned short* __restrict__ Wg_bf,
                             const float* __restrict__ Gs, unsigned short* __restrict__ GsT,
                             const float* __restrict__ bg, float* __restrict__ bias1,
                             const float* __restrict__ Wgs, unsigned short* __restrict__ WgsT,
                             const float* __restrict__ bdec, float* __restrict__ dec,
                             float* __restrict__ scores) {
  const int b = blockIdx.x;
  if (b < 12544) {
    cast8_body(gf, gf_bf, b, 3211264);
  } else if (b < 20736) {
    cast8_body(Wg, Wg_bf, b - 12544, 2097152);
  } else if (b < 24832) {
    int bb = b - 20736;                       // 4096 blocks: 32 col-tiles x 128 row-tiles
    trans32_body(Gs, GsT, 4096, 1024, bb & 31, bb >> 5);
  } else if (b < 24896) {
    int bb = b - 24832;                       // 64 blocks: 4 j-chunks x 16 k-chunks
    int j = (bb & 3) * 256 + threadIdx.x;
    int k0 = (bb >> 2) * 256;
    float acc = 0.f;
    for (int k = 0; k < 256; ++k) acc += bg[k0 + k] * Gs[(size_t)(k0 + k) * 1024 + j];
    atomicAdd(&bias1[j], acc);
  } else if (b < 25920) {
    int bb = b - 24896;                       // 1024 blocks: Wgs transpose
    trans32_body(Wgs, WgsT, 1024, 1024, bb & 31, bb >> 5);
  } else if (b < 26048) {
    int i = (b - 25920) * 256 + threadIdx.x;  // 128 blocks: dec init (32x1024)
    dec[i] = bdec[i & 1023];
  } else {
    int i = (b - 26048) * 256 + threadIdx.x;  // 7 blocks zero 1568 float4 = 6272 floats
    if (i < 1568) ((float4*)scores)[i] = make_float4(0.f, 0.f, 0.f, 0.f);
  }
}

// ---------------- dec += s_t_hat @ Wdec (k-split, LDS-staged, proven structure) -----
__global__ void dec_accum_kernel(const float* __restrict__ sth, const float* __restrict__ Wdec,
                                 float* __restrict__ dec) {
  __shared__ float ss[32][128];
  const int tid = threadIdx.x;
  const int k0 = blockIdx.y * 128;
  for (int i = tid; i < 32 * 128; i += 256) {
    int bb = i >> 7, kk = i & 127;
    ss[bb][kk] = sth[bb * 1024 + k0 + kk];
  }
  __syncthreads();
  const int j = blockIdx.x * 256 + tid;
  float acc[32];
#pragma unroll
  for (int b = 0; b < 32; ++b) acc[b] = 0.f;
  for (int kk = 0; kk < 128; ++kk) {
    float w = Wdec[(size_t)(k0 + kk) * 1024 + j];
#pragma unroll
    for (int b = 0; b < 32; ++b) acc[b] += ss[b][kk] * w;
  }
  for (int b = 0; b < 32; ++b) atomicAdd(&dec[b * 1024 + j], acc[b]);
}

// ---------------- tiled GEMM, BK=64, dbuf, LDS chunk-XOR swizzle: C = A@BT^T (+bias)
// Bank-conflict fix (T2, rule #21 both-sides): LDS dest stays LINEAR (gload_lds
// requirement); the GLOBAL source k-chunk is pre-swizzled per row
// (chunk' = chunk ^ ((row>>1)&3)), and the fragment read applies the same XOR
// (quad ^ ((col>>1)&3); wm/tf terms are ==0 mod 4 so the XOR is fragment-uniform).
// Old pattern: 16-lane b128 phase hit 2 bank-groups (8-way conflict); new: 8 groups
// (2-way = free, m136). Stage coalescing unchanged (chunks permute within each row).
template <int BM, int BN, bool HAS_BIAS, bool WRITE_F32, bool WRITE_BF16, bool SWAPXY>
__global__ __launch_bounds__(256, 2) void gemm_tile_kernel(
    const unsigned short* __restrict__ A, const unsigned short* __restrict__ BT,
    const float* __restrict__ bias, float* __restrict__ Cf,
    unsigned short* __restrict__ Cb, int M, int N, int K) {
  constexpr int AF = BM / 32;
  constexpr int BF = BN / 32;
  constexpr int ASLAB = BM * 64;     // BYTES per 32-k slab
  constexpr int BSLAB = BN * 64;
  constexpr int ABUF = 2 * ASLAB;
  constexpr int BBUF = 2 * BSLAB;
  __shared__ unsigned short lds_a[BM * 128];
  __shared__ unsigned short lds_b[BN * 128];
  const int tid = threadIdx.x;
  const int lane = tid & 63;
  const int wave = tid >> 6;
  const int wm = wave >> 1, wn = wave & 1;
  const int quad = lane >> 4, col = lane & 15;

  const int gx = (int)gridDim.x;
  const int nwg = gx * (int)gridDim.y;
  const int bid = (int)blockIdx.y * gx + (int)blockIdx.x;
  const int swz = (bid & 7) * (nwg >> 3) + (bid >> 3);
  const int bx = swz % gx, by = swz / gx;
  const int m0 = (SWAPXY ? bx : by) * BM;
  const int n0 = (SWAPXY ? by : bx) * BN;

  floatx4 acc[AF][BF] = {};

  const int srow = tid >> 2;                       // 0..63 (row within 64-row block)
  const int skoff = ((tid & 3) ^ ((tid >> 3) & 3)) * 8;   // pre-swizzled source chunk
  const unsigned short* a_ptr = A + (size_t)(m0 + srow) * K + skoff;
  const unsigned short* b_ptr = BT + (size_t)(n0 + srow) * K + skoff;
  const size_t rowskip = (size_t)64 * K;
  char* const la_dst = (char*)lds_a + tid * 16;    // linear LDS dest
  char* const lb_dst = (char*)lds_b + tid * 16;
  const int cx = (quad ^ ((col >> 1) & 3)) * 16;   // swizzled read chunk offset

  // prologue: stage K-step 0 into buffer 0
#pragma unroll
  for (int h = 0; h < BM / 64; ++h)
#pragma unroll
    for (int s = 0; s < 2; ++s)
      __builtin_amdgcn_global_load_lds((const GLOBAL_AS void*)(a_ptr + h * rowskip + s * 32),
                                       (LDS_AS void*)(la_dst + s * ASLAB + h * 4096), 16, 0, 0);
#pragma unroll
  for (int h = 0; h < BN / 64; ++h)
#pragma unroll
    for (int s = 0; s < 2; ++s)
      __builtin_amdgcn_global_load_lds((const GLOBAL_AS void*)(b_ptr + h * rowskip + s * 32),
                                       (LDS_AS void*)(lb_dst + s * BSLAB + h * 4096), 16, 0, 0);
  a_ptr += 64; b_ptr += 64;
  __syncthreads();

  const int NT = K >> 6;
  int cur = 0;
  for (int t = 0; t < NT; ++t) {
    if (t + 1 < NT) {            // stage next K-step into the other buffer FIRST
      char* la = la_dst + (cur ^ 1) * ABUF;
      char* lb = lb_dst + (cur ^ 1) * BBUF;
#pragma unroll
      for (int h = 0; h < BM / 64; ++h)
#pragma unroll
        for (int s = 0; s < 2; ++s)
          __builtin_amdgcn_global_load_lds((const GLOBAL_AS void*)(a_ptr + h * rowskip + s * 32),
                                           (LDS_AS void*)(la + s * ASLAB + h * 4096), 16, 0, 0);
#pragma unroll
      for (int h = 0; h < BN / 64; ++h)
#pragma unroll
        for (int s = 0; s < 2; ++s)
          __builtin_amdgcn_global_load_lds((const GLOBAL_AS void*)(b_ptr + h * rowskip + s * 32),
                                           (LDS_AS void*)(lb + s * BSLAB + h * 4096), 16, 0, 0);
      a_ptr += 64; b_ptr += 64;
    }
    const char* pa = (const char*)lds_a + cur * ABUF;
    const char* pb = (const char*)lds_b + cur * BBUF;
#pragma unroll
    for (int s = 0; s < 2; ++s) {
      short8 af[AF], bf[BF];
#pragma unroll
      for (int tf = 0; tf < AF; ++tf)
        af[tf] = *(const short8*)(pa + s * ASLAB + (wm * (BM / 2) + tf * 16 + col) * 64 + cx);
#pragma unroll
      for (int tf = 0; tf < BF; ++tf)
        bf[tf] = *(const short8*)(pb + s * BSLAB + (wn * (BN / 2) + tf * 16 + col) * 64 + cx);
#pragma unroll
      for (int tm = 0; tm < AF; ++tm)
#pragma unroll
        for (int tn = 0; tn < BF; ++tn)
          acc[tm][tn] = __builtin_amdgcn_mfma_f32_16x16x32_bf16(af[tm], bf[tn], acc[tm][tn], 0, 0, 0);
    }
    __syncthreads();
    cur ^= 1;
  }

#pragma unroll
  for (int tm = 0; tm < AF; ++tm) {
    const int mg = m0 + wm * (BM / 2) + tm * 16 + quad * 4;
#pragma unroll
    for (int tn = 0; tn < BF; ++tn) {
      const int ng = n0 + wn * (BN / 2) + tn * 16 + col;
      const float bv = HAS_BIAS ? bias[ng] : 0.0f;
#pragma unroll
      for (int r = 0; r < 4; ++r) {
        const float val = acc[tm][tn][r] + bv;
        if (WRITE_F32) Cf[(size_t)(mg + r) * N + ng] = val;
        if (WRITE_BF16) Cb[(size_t)(mg + r) * N + ng] = f2bf_rne(val);
      }
    }
  }
}

// ---------------- GEMM3 (128x64 tile, BK=64, dbuf, swizzled) + scores epilogue ------
__global__ __launch_bounds__(256, 2) void gemm_scores_kernel(
    const unsigned short* __restrict__ A, const unsigned short* __restrict__ BT,
    const float* __restrict__ dec, const float* __restrict__ cov,
    const float* __restrict__ v, float* __restrict__ scores, int M, int N, int K) {
  constexpr int ASLAB = 8192, ABUF = 16384;
  constexpr int BSLAB = 4096, BBUF = 8192;
  __shared__ unsigned short lds_a[128 * 128];
  __shared__ unsigned short lds_b[64 * 128];
  const int tid = threadIdx.x;
  const int lane = tid & 63;
  const int wave = tid >> 6;
  const int wm = wave >> 1, wn = wave & 1;
  const int quad = lane >> 4, col = lane & 15;

  const int gx = (int)gridDim.x;
  const int nwg = gx * (int)gridDim.y;
  const int bid = (int)blockIdx.y * gx + (int)blockIdx.x;
  const int swz = (bid & 7) * (nwg >> 3) + (bid >> 3);
  const int m0 = (swz / gx) * 128, n0 = (swz % gx) * 64;

  floatx4 acc[4][2] = {};

  const int srow = tid >> 2;
  const int skoff = ((tid & 3) ^ ((tid >> 3) & 3)) * 8;   // pre-swizzled source chunk
  const unsigned short* a_ptr = A + (size_t)(m0 + srow) * K + skoff;
  const unsigned short* b_ptr = BT + (size_t)(n0 + srow) * K + skoff;
  const size_t rowskip = (size_t)64 * K;
  char* const la_dst = (char*)lds_a + tid * 16;
  char* const lb_dst = (char*)lds_b + tid * 16;
  const int cx = (quad ^ ((col >> 1) & 3)) * 16;          // swizzled read chunk offset

#pragma unroll
  for (int h = 0; h < 2; ++h)
#pragma unroll
    for (int s = 0; s < 2; ++s)
      __builtin_amdgcn_global_load_lds((const GLOBAL_AS void*)(a_ptr + h * rowskip + s * 32),
                                       (LDS_AS void*)(la_dst + s * ASLAB + h * 4096), 16, 0, 0);
#pragma unroll
  for (int s = 0; s < 2; ++s)
    __builtin_amdgcn_global_load_lds((const GLOBAL_AS void*)(b_ptr + s * 32),
                                     (LDS_AS void*)(lb_dst + s * BSLAB), 16, 0, 0);
  a_ptr += 64; b_ptr += 64;
  __syncthreads();

  const int NT = K >> 6;
  int cur = 0;
  for (int t = 0; t < NT; ++t) {
    if (t + 1 < NT) {
      char* la = la_dst + (cur ^ 1) * ABUF;
      char* lb = lb_dst + (cur ^ 1) * BBUF;
#pragma unroll
      for (int h = 0; h < 2; ++h)
#pragma unroll
        for (int s = 0; s < 2; ++s)
          __builtin_amdgcn_global_load_lds((const GLOBAL_AS void*)(a_ptr + h * rowskip + s * 32),
                                           (LDS_AS void*)(la + s * ASLAB + h * 4096), 16, 0, 0);
#pragma unroll
      for (int s = 0; s < 2; ++s)
        __builtin_amdgcn_global_load_lds((const GLOBAL_AS void*)(b_ptr + s * 32),
                                         (LDS_AS void*)(lb + s * BSLAB), 16, 0, 0);
      a_ptr += 64; b_ptr += 64;
    }
    const char* pa = (const char*)lds_a + cur * ABUF;
    const char* pb = (const char*)lds_b + cur * BBUF;
#pragma unroll
    for (int s = 0; s < 2; ++s) {
      short8 af[4], bf[2];
#pragma unroll
      for (int tf = 0; tf < 4; ++tf)
        af[tf] = *(const short8*)(pa + s * ASLAB + (wm * 64 + tf * 16 + col) * 64 + cx);
#pragma unroll
      for (int tf = 0; tf < 2; ++tf)
        bf[tf] = *(const short8*)(pb + s * BSLAB + (wn * 32 + tf * 16 + col) * 64 + cx);
#pragma unroll
      for (int tm = 0; tm < 4; ++tm)
#pragma unroll
        for (int tn = 0; tn < 2; ++tn)
          acc[tm][tn] = __builtin_amdgcn_mfma_f32_16x16x32_bf16(af[tm], bf[tn], acc[tm][tn], 0, 0, 0);
    }
    __syncthreads();
    cur ^= 1;
  }

  const int n_base = n0 + wn * 32;
  float vv[2];
#pragma unroll
  for (int tn = 0; tn < 2; ++tn) vv[tn] = v[n_base + tn * 16 + col];
#pragma unroll
  for (int tm = 0; tm < 4; ++tm) {
#pragma unroll
    for (int r = 0; r < 4; ++r) {
      const int row = m0 + wm * 64 + tm * 16 + quad * 4 + r;
      const int b = row / 196;
      const float cw = cov[row];
      const float* dr = dec + b * 1024 + n_base;
      float s = 0.f;
#pragma unroll
      for (int tn = 0; tn < 2; ++tn)
        s += tanhf(acc[tm][tn][r] + dr[tn * 16 + col] + cw) * vv[tn];
      s += __shfl_xor(s, 1, 64);
      s += __shfl_xor(s, 2, 64);
      s += __shfl_xor(s, 4, 64);
      s += __shfl_xor(s, 8, 64);
      if ((lane & 15) == 0) atomicAdd(&scores[row], s);
    }
  }
}

// ---------------- softmax over 196 regions: alpha + coverage outputs ----------------
__global__ void softmax_kernel(const float* __restrict__ scores, const float* __restrict__ cov,
                               float* __restrict__ alpha_ws, float* __restrict__ out) {
  const int b = blockIdx.x, tid = threadIdx.x;
  const int lane = tid & 63, wid = tid >> 6;
  __shared__ float red[8];
  float s = (tid < 196) ? scores[b * 196 + tid] : -1e30f;
  float m = s;
  for (int off = 32; off > 0; off >>= 1) m = fmaxf(m, __shfl_xor(m, off, 64));
  if (lane == 0) red[wid] = m;
  __syncthreads();
  m = fmaxf(fmaxf(red[0], red[1]), fmaxf(red[2], red[3]));
  float e = (tid < 196) ? __expf(s - m) : 0.f;
  float t = e;
  for (int off = 32; off > 0; off >>= 1) t += __shfl_xor(t, off, 64);
  if (lane == 0) red[4 + wid] = t;
  __syncthreads();
  const float tot = red[4] + red[5] + red[6] + red[7];
  const float a = e / tot;
  if (tid < 196) {
    alpha_ws[b * 196 + tid] = a;
    out[32768 + b * 196 + tid] = cov[b * 196 + tid] + a;   // coverage_new
    out[32768 + 6272 + b * 196 + tid] = a;                 // alpha_a
  }
}

// ---------------- context: c_img[b, :] = sum_t alpha[b,t] * gstar[b,t,:] ------------
__global__ __launch_bounds__(256) void ctx_kernel(const float* __restrict__ alpha,
                                                  const float* __restrict__ gstar,
                                                  float* __restrict__ out) {
  const int b = blockIdx.y;
  const int colbase = blockIdx.x * 128;
  const int c = threadIdx.x & 127;
  const int half = threadIdx.x >> 7;
  const float* g = gstar + ((size_t)b * 196 + half * 98) * 1024 + colbase + c;
  const float* al = alpha + b * 196 + half * 98;
  float acc = 0.f;
#pragma unroll 7
  for (int t = 0; t < 98; ++t) acc += al[t] * g[(size_t)t * 1024];
  __shared__ float part[256];
  part[threadIdx.x] = acc;
  __syncthreads();
  if (threadIdx.x < 128)
    out[b * 1024 + colbase + threadIdx.x] = part[threadIdx.x] + part[threadIdx.x + 128];
}

// ---------------- launch ----------------
extern "C" void kernel_launch(void* const* d_in, const int* in_sizes, int n_in,
                              void* d_out, int out_size, void* d_ws, size_t ws_size,
                              hipStream_t stream) {
  (void)in_sizes; (void)n_in; (void)out_size; (void)ws_size;
  const float* gf   = (const float*)d_in[0];   // [6272, 4096]
  const float* sth  = (const float*)d_in[1];   // [32, 1024]
  const float* cov  = (const float*)d_in[2];   // [6272]
  const float* Wg   = (const float*)d_in[3];   // [4096, 4096]
  const float* bg   = (const float*)d_in[4];   // [4096]
  const float* Gs   = (const float*)d_in[5];   // [4096, 1024]
  const float* bgs  = (const float*)d_in[6];   // [1024]
  const float* Wgs  = (const float*)d_in[7];   // [1024, 1024]
  const float* Wdec = (const float*)d_in[8];   // [1024, 1024]
  const float* bdec = (const float*)d_in[9];   // [1024]
  const float* v    = (const float*)d_in[10];  // [1024]
  float* out = (float*)d_out;

  char* ws = (char*)d_ws;
  // Memory map (lifetimes):
  //   [0, 51.38M)          gf_bf16 [prep1 -> GEMM2]
  //   [51.38M, 84.93M)     Wg_bf16 [prep1 -> GEMM1]
  //   [51.38M, 77.07M)     gstar_f32 [GEMM2 -> ctx]          (over Wg_bf, dead by then)
  //   [84.93M, 93.32M)     GsT_bf16 [prep1 -> GEMM1]
  //   [84.93M, 97.78M)     gstar_bf16 [GEMM2 -> GEMM3]       (over GsT, dead by then)
  //   [102.76M, 111.15M)   C1T_bf16 [GEMM1 -> GEMM2]
  //   [111.15M, 113.25M)   WgsT_bf16 [prep1 -> GEMM3]
  //   [113.25M+)           bias1, dec, scores, alpha (small)
  unsigned short* gf_bf   = (unsigned short*)(ws + 0);
  unsigned short* Wg_bf   = (unsigned short*)(ws + 51380224);
  float*          gstar_f = (float*)(ws + 51380224);
  unsigned short* GsT     = (unsigned short*)(ws + 84934656);
  unsigned short* gstar_b = (unsigned short*)(ws + 84934656);
  unsigned short* C1T_b   = (unsigned short*)(ws + 102760448);
  unsigned short* WgsT    = (unsigned short*)(ws + 111149056);
  float*          bias1   = (float*)(ws + 113246208);
  float*          dec     = (float*)(ws + 113262592);
  float*          scores  = (float*)(ws + 113393664);
  float*          alpha   = (float*)(ws + 113426432);

  // 1. bias1 init (bgs) + fused prep1: casts, transposes, bias1 accum, dec init, zero
  hipMemcpyAsync(bias1, bgs, 4096, hipMemcpyDeviceToDevice, stream);
  prep1_kernel<<<26055, 256, 0, stream>>>(gf, gf_bf, Wg, Wg_bf, Gs, GsT, bg, bias1,
                                          Wgs, WgsT, bdec, dec, scores);
  // 2. dec += sth @ Wdec (k-split x8, LDS-staged, 32 blocks)
  dec_accum_kernel<<<dim3(4, 8), 256, 0, stream>>>(sth, Wdec, dec);
  // 3. GEMM1: C1T[1024,4096] = GsT @ Wg^T, bf16 out. 128x64, SWAPXY, 512 blocks.
  gemm_tile_kernel<128, 64, false, false, true, true><<<dim3(8, 64), 256, 0, stream>>>(
      GsT, Wg_bf, nullptr, nullptr, C1T_b, 1024, 4096, 4096);
  // 4. GEMM2: g_star[6272,1024] = gf @ C1 + bias1; fp32 AND bf16 out (fused cast).
  //    128x128, swizzled LDS, grid (8 n, 49 m) = 392 blocks.
  gemm_tile_kernel<128, 128, true, true, true, false><<<dim3(8, 49), 256, 0, stream>>>(
      gf_bf, C1T_b, bias1, gstar_f, gstar_b, 6272, 1024, 4096);
  // 5. GEMM3 fused with scores epilogue (w_g_star never materialized). 784 blocks.
  gemm_scores_kernel<<<dim3(16, 49), 256, 0, stream>>>(
      gstar_b, WgsT, dec, cov, v, scores, 6272, 1024, 1024);
  // 6. softmax (alpha + coverage outputs), then parallel context
  softmax_kernel<<<32, 256, 0, stream>>>(scores, cov, alpha, out);
  ctx_kernel<<<dim3(8, 32), 256, 0, stream>>>(alpha, gstar_f, out);
}

// Round 7
// 478.855 us; speedup vs baseline: 1.4276x; 1.0173x over previous
//
#include <hip/hip_runtime.h>
#include <hip/hip_bf16.h>

typedef __attribute__((ext_vector_type(8))) short short8;
typedef __attribute__((ext_vector_type(4))) float floatx4;

#define GLOBAL_AS __attribute__((address_space(1)))
#define LDS_AS    __attribute__((address_space(3)))

__device__ __forceinline__ unsigned short f2bf_rne(float x) {
  unsigned int u = __float_as_uint(x);
  u += 0x7fffu + ((u >> 16) & 1u);
  return (unsigned short)(u >> 16);
}

// ---------------- device helpers for fused prep kernel ----------------
__device__ __forceinline__ void cast8_body(const float* __restrict__ in,
                                           unsigned short* __restrict__ out,
                                           int blk, int n8) {
  int i = blk * 256 + threadIdx.x;
  if (i >= n8) return;
  const float4* p = (const float4*)in;
  float4 v0 = p[2 * i], v1 = p[2 * i + 1];
  short8 o;
  o[0] = (short)f2bf_rne(v0.x); o[1] = (short)f2bf_rne(v0.y);
  o[2] = (short)f2bf_rne(v0.z); o[3] = (short)f2bf_rne(v0.w);
  o[4] = (short)f2bf_rne(v1.x); o[5] = (short)f2bf_rne(v1.y);
  o[6] = (short)f2bf_rne(v1.z); o[7] = (short)f2bf_rne(v1.w);
  *(short8*)(out + 8 * (size_t)i) = o;
}

__device__ __forceinline__ void trans32_body(const float* __restrict__ in,
                                             unsigned short* __restrict__ out,
                                             int R, int C, int bx, int by) {
  __shared__ unsigned short tile[32][33];
  int tx = threadIdx.x & 31, ty = threadIdx.x >> 5;
  int r0 = by * 32, c0 = bx * 32;
#pragma unroll
  for (int j = 0; j < 32; j += 8)
    tile[ty + j][tx] = f2bf_rne(in[(size_t)(r0 + ty + j) * C + c0 + tx]);
  __syncthreads();
#pragma unroll
  for (int j = 0; j < 32; j += 8)
    out[(size_t)(c0 + ty + j) * R + r0 + tx] = tile[tx][ty + j];
}

// ---------------- prep1: cast gf, cast Wg, transpose Gs, bias1 accum, transpose Wgs,
//                  init dec = bdec broadcast, zero scores ----------------------------
// bias1 must be pre-initialized to bgs via hipMemcpyAsync before this launch.
// dec_accum_kernel (separate launch) adds sth @ Wdec on top of the init written here.
__global__ void prep1_kernel(const float* __restrict__ gf, unsigned short* __restrict__ gf_bf,
                             const float* __restrict__ Wg, unsigned short* __restrict__ Wg_bf,
                             const float* __restrict__ Gs, unsigned short* __restrict__ GsT,
                             const float* __restrict__ bg, float* __restrict__ bias1,
                             const float* __restrict__ Wgs, unsigned short* __restrict__ WgsT,
                             const float* __restrict__ bdec, float* __restrict__ dec,
                             float* __restrict__ scores) {
  const int b = blockIdx.x;
  if (b < 12544) {
    cast8_body(gf, gf_bf, b, 3211264);
  } else if (b < 20736) {
    cast8_body(Wg, Wg_bf, b - 12544, 2097152);
  } else if (b < 24832) {
    int bb = b - 20736;                       // 4096 blocks: 32 col-tiles x 128 row-tiles
    trans32_body(Gs, GsT, 4096, 1024, bb & 31, bb >> 5);
  } else if (b < 24896) {
    int bb = b - 24832;                       // 64 blocks: 4 j-chunks x 16 k-chunks
    int j = (bb & 3) * 256 + threadIdx.x;
    int k0 = (bb >> 2) * 256;
    float acc = 0.f;
    for (int k = 0; k < 256; ++k) acc += bg[k0 + k] * Gs[(size_t)(k0 + k) * 1024 + j];
    atomicAdd(&bias1[j], acc);
  } else if (b < 25920) {
    int bb = b - 24896;                       // 1024 blocks: Wgs transpose
    trans32_body(Wgs, WgsT, 1024, 1024, bb & 31, bb >> 5);
  } else if (b < 26048) {
    int i = (b - 25920) * 256 + threadIdx.x;  // 128 blocks: dec init (32x1024)
    dec[i] = bdec[i & 1023];
  } else {
    int i = (b - 26048) * 256 + threadIdx.x;  // 7 blocks zero 1568 float4 = 6272 floats
    if (i < 1568) ((float4*)scores)[i] = make_float4(0.f, 0.f, 0.f, 0.f);
  }
}

// ---------------- dec += s_t_hat @ Wdec (k-split, LDS-staged, proven structure) -----
__global__ void dec_accum_kernel(const float* __restrict__ sth, const float* __restrict__ Wdec,
                                 float* __restrict__ dec) {
  __shared__ float ss[32][128];
  const int tid = threadIdx.x;
  const int k0 = blockIdx.y * 128;
  for (int i = tid; i < 32 * 128; i += 256) {
    int bb = i >> 7, kk = i & 127;
    ss[bb][kk] = sth[bb * 1024 + k0 + kk];
  }
  __syncthreads();
  const int j = blockIdx.x * 256 + tid;
  float acc[32];
#pragma unroll
  for (int b = 0; b < 32; ++b) acc[b] = 0.f;
  for (int kk = 0; kk < 128; ++kk) {
    float w = Wdec[(size_t)(k0 + kk) * 1024 + j];
#pragma unroll
    for (int b = 0; b < 32; ++b) acc[b] += ss[b][kk] * w;
  }
  for (int b = 0; b < 32; ++b) atomicAdd(&dec[b * 1024 + j], acc[b]);
}

// ---------------- tiled GEMM, BK=64, SINGLE-buffered LDS (m97 cell): C=A@BT^T (+bias)
// m97-anchored structure: 32 KB LDS (128x128) -> 4 resident blocks/CU
// (__launch_bounds__(256,4), 4 blocks x 32 KB = 128 KB <= 160). Latency hiding comes
// from implicit cross-block wave overlap (m114), which m99/m100 showed dominates
// explicit dbuf. R2-R6 had 2-resident at 64-80 KB: the untested cell was
// 128x128 AI + 4-resident, which is m97's exact 874 TF configuration.
// Conflict-free XOR chunk swizzle kept (conflicts measured 0 in R6):
// source chunk' = chunk ^ ((row>>1)&3), read chunk XOR (quad ^ ((col>>1)&3)).
// XCD-chunked swizzle + SWAPXY kept (FETCH 212->62 MB, R2).
template <int BM, int BN, bool HAS_BIAS, bool WRITE_F32, bool WRITE_BF16, bool SWAPXY>
__global__ __launch_bounds__(256, 4) void gemm_tile_kernel(
    const unsigned short* __restrict__ A, const unsigned short* __restrict__ BT,
    const float* __restrict__ bias, float* __restrict__ Cf,
    unsigned short* __restrict__ Cb, int M, int N, int K) {
  constexpr int AF = BM / 32;
  constexpr int BF = BN / 32;
  constexpr int ASLAB = BM * 64;     // BYTES per 32-k slab
  constexpr int BSLAB = BN * 64;
  __shared__ unsigned short lds_a[BM * 64];   // single buffer: 2 slabs of BM*32 shorts
  __shared__ unsigned short lds_b[BN * 64];
  const int tid = threadIdx.x;
  const int lane = tid & 63;
  const int wave = tid >> 6;
  const int wm = wave >> 1, wn = wave & 1;
  const int quad = lane >> 4, col = lane & 15;

  const int gx = (int)gridDim.x;
  const int nwg = gx * (int)gridDim.y;
  const int bid = (int)blockIdx.y * gx + (int)blockIdx.x;
  const int swz = (bid & 7) * (nwg >> 3) + (bid >> 3);
  const int bx = swz % gx, by = swz / gx;
  const int m0 = (SWAPXY ? bx : by) * BM;
  const int n0 = (SWAPXY ? by : bx) * BN;

  floatx4 acc[AF][BF] = {};

  const int srow = tid >> 2;                              // 0..63
  const int skoff = ((tid & 3) ^ ((tid >> 3) & 3)) * 8;   // pre-swizzled source chunk
  const unsigned short* a_ptr = A + (size_t)(m0 + srow) * K + skoff;
  const unsigned short* b_ptr = BT + (size_t)(n0 + srow) * K + skoff;
  const size_t rowskip = (size_t)64 * K;
  char* const la_dst = (char*)lds_a + tid * 16;           // linear LDS dest
  char* const lb_dst = (char*)lds_b + tid * 16;
  const int cx = (quad ^ ((col >> 1) & 3)) * 16;          // swizzled read chunk offset

  for (int kt = 0; kt < K; kt += 64) {
    __syncthreads();             // readers of previous tile done
#pragma unroll
    for (int h = 0; h < BM / 64; ++h)
#pragma unroll
      for (int s = 0; s < 2; ++s)
        __builtin_amdgcn_global_load_lds((const GLOBAL_AS void*)(a_ptr + h * rowskip + s * 32),
                                         (LDS_AS void*)(la_dst + s * ASLAB + h * 4096), 16, 0, 0);
#pragma unroll
    for (int h = 0; h < BN / 64; ++h)
#pragma unroll
      for (int s = 0; s < 2; ++s)
        __builtin_amdgcn_global_load_lds((const GLOBAL_AS void*)(b_ptr + h * rowskip + s * 32),
                                         (LDS_AS void*)(lb_dst + s * BSLAB + h * 4096), 16, 0, 0);
    a_ptr += 64; b_ptr += 64;
    __syncthreads();             // drain: tile ready
#pragma unroll
    for (int s = 0; s < 2; ++s) {
      short8 af[AF], bf[BF];
#pragma unroll
      for (int tf = 0; tf < AF; ++tf)
        af[tf] = *(const short8*)((const char*)lds_a + s * ASLAB +
                                  (wm * (BM / 2) + tf * 16 + col) * 64 + cx);
#pragma unroll
      for (int tf = 0; tf < BF; ++tf)
        bf[tf] = *(const short8*)((const char*)lds_b + s * BSLAB +
                                  (wn * (BN / 2) + tf * 16 + col) * 64 + cx);
#pragma unroll
      for (int tm = 0; tm < AF; ++tm)
#pragma unroll
        for (int tn = 0; tn < BF; ++tn)
          acc[tm][tn] = __builtin_amdgcn_mfma_f32_16x16x32_bf16(af[tm], bf[tn], acc[tm][tn], 0, 0, 0);
    }
  }

#pragma unroll
  for (int tm = 0; tm < AF; ++tm) {
    const int mg = m0 + wm * (BM / 2) + tm * 16 + quad * 4;
#pragma unroll
    for (int tn = 0; tn < BF; ++tn) {
      const int ng = n0 + wn * (BN / 2) + tn * 16 + col;
      const float bv = HAS_BIAS ? bias[ng] : 0.0f;
#pragma unroll
      for (int r = 0; r < 4; ++r) {
        const float val = acc[tm][tn][r] + bv;
        if (WRITE_F32) Cf[(size_t)(mg + r) * N + ng] = val;
        if (WRITE_BF16) Cb[(size_t)(mg + r) * N + ng] = f2bf_rne(val);
      }
    }
  }
}

// ---------------- GEMM3 (128x64, single-buffer, swizzled) + scores epilogue ---------
__global__ __launch_bounds__(256, 4) void gemm_scores_kernel(
    const unsigned short* __restrict__ A, const unsigned short* __restrict__ BT,
    const float* __restrict__ dec, const float* __restrict__ cov,
    const float* __restrict__ v, float* __restrict__ scores, int M, int N, int K) {
  constexpr int ASLAB = 8192;   // 128 rows x 64 B per 32-k slab
  constexpr int BSLAB = 4096;   // 64 rows x 64 B
  __shared__ unsigned short lds_a[128 * 64];   // 16 KB
  __shared__ unsigned short lds_b[64 * 64];    // 8 KB
  const int tid = threadIdx.x;
  const int lane = tid & 63;
  const int wave = tid >> 6;
  const int wm = wave >> 1, wn = wave & 1;
  const int quad = lane >> 4, col = lane & 15;

  const int gx = (int)gridDim.x;
  const int nwg = gx * (int)gridDim.y;
  const int bid = (int)blockIdx.y * gx + (int)blockIdx.x;
  const int swz = (bid & 7) * (nwg >> 3) + (bid >> 3);
  const int m0 = (swz / gx) * 128, n0 = (swz % gx) * 64;

  floatx4 acc[4][2] = {};

  const int srow = tid >> 2;
  const int skoff = ((tid & 3) ^ ((tid >> 3) & 3)) * 8;
  const unsigned short* a_ptr = A + (size_t)(m0 + srow) * K + skoff;
  const unsigned short* b_ptr = BT + (size_t)(n0 + srow) * K + skoff;
  const size_t rowskip = (size_t)64 * K;
  char* const la_dst = (char*)lds_a + tid * 16;
  char* const lb_dst = (char*)lds_b + tid * 16;
  const int cx = (quad ^ ((col >> 1) & 3)) * 16;

  for (int kt = 0; kt < K; kt += 64) {
    __syncthreads();
#pragma unroll
    for (int h = 0; h < 2; ++h)
#pragma unroll
      for (int s = 0; s < 2; ++s)
        __builtin_amdgcn_global_load_lds((const GLOBAL_AS void*)(a_ptr + h * rowskip + s * 32),
                                         (LDS_AS void*)(la_dst + s * ASLAB + h * 4096), 16, 0, 0);
#pragma unroll
    for (int s = 0; s < 2; ++s)
      __builtin_amdgcn_global_load_lds((const GLOBAL_AS void*)(b_ptr + s * 32),
                                       (LDS_AS void*)(lb_dst + s * BSLAB), 16, 0, 0);
    a_ptr += 64; b_ptr += 64;
    __syncthreads();
#pragma unroll
    for (int s = 0; s < 2; ++s) {
      short8 af[4], bf[2];
#pragma unroll
      for (int tf = 0; tf < 4; ++tf)
        af[tf] = *(const short8*)((const char*)lds_a + s * ASLAB +
                                  (wm * 64 + tf * 16 + col) * 64 + cx);
#pragma unroll
      for (int tf = 0; tf < 2; ++tf)
        bf[tf] = *(const short8*)((const char*)lds_b + s * BSLAB +
                                  (wn * 32 + tf * 16 + col) * 64 + cx);
#pragma unroll
      for (int tm = 0; tm < 4; ++tm)
#pragma unroll
        for (int tn = 0; tn < 2; ++tn)
          acc[tm][tn] = __builtin_amdgcn_mfma_f32_16x16x32_bf16(af[tm], bf[tn], acc[tm][tn], 0, 0, 0);
    }
  }

  const int n_base = n0 + wn * 32;
  float vv[2];
#pragma unroll
  for (int tn = 0; tn < 2; ++tn) vv[tn] = v[n_base + tn * 16 + col];
#pragma unroll
  for (int tm = 0; tm < 4; ++tm) {
#pragma unroll
    for (int r = 0; r < 4; ++r) {
      const int row = m0 + wm * 64 + tm * 16 + quad * 4 + r;
      const int b = row / 196;
      const float cw = cov[row];
      const float* dr = dec + b * 1024 + n_base;
      float s = 0.f;
#pragma unroll
      for (int tn = 0; tn < 2; ++tn)
        s += tanhf(acc[tm][tn][r] + dr[tn * 16 + col] + cw) * vv[tn];
      s += __shfl_xor(s, 1, 64);
      s += __shfl_xor(s, 2, 64);
      s += __shfl_xor(s, 4, 64);
      s += __shfl_xor(s, 8, 64);
      if ((lane & 15) == 0) atomicAdd(&scores[row], s);
    }
  }
}

// ---------------- softmax over 196 regions: alpha + coverage outputs ----------------
__global__ void softmax_kernel(const float* __restrict__ scores, const float* __restrict__ cov,
                               float* __restrict__ alpha_ws, float* __restrict__ out) {
  const int b = blockIdx.x, tid = threadIdx.x;
  const int lane = tid & 63, wid = tid >> 6;
  __shared__ float red[8];
  float s = (tid < 196) ? scores[b * 196 + tid] : -1e30f;
  float m = s;
  for (int off = 32; off > 0; off >>= 1) m = fmaxf(m, __shfl_xor(m, off, 64));
  if (lane == 0) red[wid] = m;
  __syncthreads();
  m = fmaxf(fmaxf(red[0], red[1]), fmaxf(red[2], red[3]));
  float e = (tid < 196) ? __expf(s - m) : 0.f;
  float t = e;
  for (int off = 32; off > 0; off >>= 1) t += __shfl_xor(t, off, 64);
  if (lane == 0) red[4 + wid] = t;
  __syncthreads();
  const float tot = red[4] + red[5] + red[6] + red[7];
  const float a = e / tot;
  if (tid < 196) {
    alpha_ws[b * 196 + tid] = a;
    out[32768 + b * 196 + tid] = cov[b * 196 + tid] + a;   // coverage_new
    out[32768 + 6272 + b * 196 + tid] = a;                 // alpha_a
  }
}

// ---------------- context: c_img[b, :] = sum_t alpha[b,t] * gstar[b,t,:] ------------
__global__ __launch_bounds__(256) void ctx_kernel(const float* __restrict__ alpha,
                                                  const float* __restrict__ gstar,
                                                  float* __restrict__ out) {
  const int b = blockIdx.y;
  const int colbase = blockIdx.x * 128;
  const int c = threadIdx.x & 127;
  const int half = threadIdx.x >> 7;
  const float* g = gstar + ((size_t)b * 196 + half * 98) * 1024 + colbase + c;
  const float* al = alpha + b * 196 + half * 98;
  float acc = 0.f;
#pragma unroll 7
  for (int t = 0; t < 98; ++t) acc += al[t] * g[(size_t)t * 1024];
  __shared__ float part[256];
  part[threadIdx.x] = acc;
  __syncthreads();
  if (threadIdx.x < 128)
    out[b * 1024 + colbase + threadIdx.x] = part[threadIdx.x] + part[threadIdx.x + 128];
}

// ---------------- launch ----------------
extern "C" void kernel_launch(void* const* d_in, const int* in_sizes, int n_in,
                              void* d_out, int out_size, void* d_ws, size_t ws_size,
                              hipStream_t stream) {
  (void)in_sizes; (void)n_in; (void)out_size; (void)ws_size;
  const float* gf   = (const float*)d_in[0];   // [6272, 4096]
  const float* sth  = (const float*)d_in[1];   // [32, 1024]
  const float* cov  = (const float*)d_in[2];   // [6272]
  const float* Wg   = (const float*)d_in[3];   // [4096, 4096]
  const float* bg   = (const float*)d_in[4];   // [4096]
  const float* Gs   = (const float*)d_in[5];   // [4096, 1024]
  const float* bgs  = (const float*)d_in[6];   // [1024]
  const float* Wgs  = (const float*)d_in[7];   // [1024, 1024]
  const float* Wdec = (const float*)d_in[8];   // [1024, 1024]
  const float* bdec = (const float*)d_in[9];   // [1024]
  const float* v    = (const float*)d_in[10];  // [1024]
  float* out = (float*)d_out;

  char* ws = (char*)d_ws;
  // Memory map (lifetimes):
  //   [0, 51.38M)          gf_bf16 [prep1 -> GEMM2]
  //   [51.38M, 84.93M)     Wg_bf16 [prep1 -> GEMM1]
  //   [51.38M, 77.07M)     gstar_f32 [GEMM2 -> ctx]          (over Wg_bf, dead by then)
  //   [84.93M, 93.32M)     GsT_bf16 [prep1 -> GEMM1]
  //   [84.93M, 97.78M)     gstar_bf16 [GEMM2 -> GEMM3]       (over GsT, dead by then)
  //   [102.76M, 111.15M)   C1T_bf16 [GEMM1 -> GEMM2]
  //   [111.15M, 113.25M)   WgsT_bf16 [prep1 -> GEMM3]
  //   [113.25M+)           bias1, dec, scores, alpha (small)
  unsigned short* gf_bf   = (unsigned short*)(ws + 0);
  unsigned short* Wg_bf   = (unsigned short*)(ws + 51380224);
  float*          gstar_f = (float*)(ws + 51380224);
  unsigned short* GsT     = (unsigned short*)(ws + 84934656);
  unsigned short* gstar_b = (unsigned short*)(ws + 84934656);
  unsigned short* C1T_b   = (unsigned short*)(ws + 102760448);
  unsigned short* WgsT    = (unsigned short*)(ws + 111149056);
  float*          bias1   = (float*)(ws + 113246208);
  float*          dec     = (float*)(ws + 113262592);
  float*          scores  = (float*)(ws + 113393664);
  float*          alpha   = (float*)(ws + 113426432);

  // 1. bias1 init (bgs) + fused prep1: casts, transposes, bias1 accum, dec init, zero
  hipMemcpyAsync(bias1, bgs, 4096, hipMemcpyDeviceToDevice, stream);
  prep1_kernel<<<26055, 256, 0, stream>>>(gf, gf_bf, Wg, Wg_bf, Gs, GsT, bg, bias1,
                                          Wgs, WgsT, bdec, dec, scores);
  // 2. dec += sth @ Wdec (k-split x8, LDS-staged, 32 blocks)
  dec_accum_kernel<<<dim3(4, 8), 256, 0, stream>>>(sth, Wdec, dec);
  // 3. GEMM1: C1T[1024,4096] = GsT @ Wg^T, bf16 out. 128x64, SWAPXY, 512 blocks.
  gemm_tile_kernel<128, 64, false, false, true, true><<<dim3(8, 64), 256, 0, stream>>>(
      GsT, Wg_bf, nullptr, nullptr, C1T_b, 1024, 4096, 4096);
  // 4. GEMM2: g_star[6272,1024] = gf @ C1 + bias1; fp32 AND bf16 out (fused cast).
  //    128x128, single-buffer 32 KB, 4 resident blocks/CU, grid (8 n, 49 m).
  gemm_tile_kernel<128, 128, true, true, true, false><<<dim3(8, 49), 256, 0, stream>>>(
      gf_bf, C1T_b, bias1, gstar_f, gstar_b, 6272, 1024, 4096);
  // 5. GEMM3 fused with scores epilogue (w_g_star never materialized). 784 blocks.
  gemm_scores_kernel<<<dim3(16, 49), 256, 0, stream>>>(
      gstar_b, WgsT, dec, cov, v, scores, 6272, 1024, 1024);
  // 6. softmax (alpha + coverage outputs), then parallel context
  softmax_kernel<<<32, 256, 0, stream>>>(scores, cov, alpha, out);
  ctx_kernel<<<dim3(8, 32), 256, 0, stream>>>(alpha, gstar_f, out);
}

// Round 10
// 462.728 us; speedup vs baseline: 1.4774x; 1.0349x over previous
//
#include <hip/hip_runtime.h>
#include <hip/hip_bf16.h>

typedef __attribute__((ext_vector_type(8))) short short8;
typedef __attribute__((ext_vector_type(4))) float floatx4;

#define GLOBAL_AS __attribute__((address_space(1)))
#define LDS_AS    __attribute__((address_space(3)))

__device__ __forceinline__ unsigned short f2bf_rne(float x) {
  unsigned int u = __float_as_uint(x);
  u += 0x7fffu + ((u >> 16) & 1u);
  return (unsigned short)(u >> 16);
}

__device__ __forceinline__ void trans32_body(const float* __restrict__ in,
                                             unsigned short* __restrict__ out,
                                             int R, int C, int bx, int by) {
  __shared__ unsigned short tile[32][33];
  int tx = threadIdx.x & 31, ty = threadIdx.x >> 5;
  int r0 = by * 32, c0 = bx * 32;
#pragma unroll
  for (int j = 0; j < 32; j += 8)
    tile[ty + j][tx] = f2bf_rne(in[(size_t)(r0 + ty + j) * C + c0 + tx]);
  __syncthreads();
#pragma unroll
  for (int j = 0; j < 32; j += 8)
    out[(size_t)(c0 + ty + j) * R + r0 + tx] = tile[tx][ty + j];
}

// ---------------- prep0: transpose Gs, transpose Wgs, bias1 accum, dec init, zero ---
// The big gf/Wg cast passes are GONE (fused into GEMM1/GEMM2 staging).
// bias1 pre-initialized to bgs via hipMemcpyAsync before this launch.
__global__ void prep0_kernel(const float* __restrict__ Gs, unsigned short* __restrict__ GsT,
                             const float* __restrict__ Wgs, unsigned short* __restrict__ WgsT,
                             const float* __restrict__ bg, float* __restrict__ bias1,
                             const float* __restrict__ bdec, float* __restrict__ dec,
                             float* __restrict__ scores) {
  const int b = blockIdx.x;
  if (b < 4096) {
    trans32_body(Gs, GsT, 4096, 1024, b & 31, b >> 5);
  } else if (b < 5120) {
    int bb = b - 4096;
    trans32_body(Wgs, WgsT, 1024, 1024, bb & 31, bb >> 5);
  } else if (b < 5184) {
    int bb = b - 5120;                        // 64 blocks: 4 j-chunks x 16 k-chunks
    int j = (bb & 3) * 256 + threadIdx.x;
    int k0 = (bb >> 2) * 256;
    float acc = 0.f;
    for (int k = 0; k < 256; ++k) acc += bg[k0 + k] * Gs[(size_t)(k0 + k) * 1024 + j];
    atomicAdd(&bias1[j], acc);
  } else if (b < 5312) {
    int i = (b - 5184) * 256 + threadIdx.x;   // 128 blocks: dec init (32x1024)
    dec[i] = bdec[i & 1023];
  } else {
    int i = (b - 5312) * 256 + threadIdx.x;   // 7 blocks zero 6272 floats
    if (i < 1568) ((float4*)scores)[i] = make_float4(0.f, 0.f, 0.f, 0.f);
  }
}

// ---------------- GEMM1 + folded dec: C1T[1024,4096] = GsT @ Wg^T (Wg fp32 direct) --
// A = GsT bf16 via global_load_lds. B = Wg fp32, reg-staged with FUSED CAST
// (load float4 pairs one K-step ahead; cvt+ds_write_b128 in the stage phase).
// Sync: __syncthreads() pairs (full drain) — R9's counted-vmcnt raced because the
// compiler may hoist the prefetch loads above global_load_lds, breaking the FIFO
// count (vmcnt(4) then left STAGEA in flight at the barrier -> garbage LDS -> NaN).
// Under a draining barrier, WRITEB needs no RAW wait (prev barrier drained its loads)
// and the prefetch still overlaps the two load streams within the phase.
// blocks 512..543 run dec += sth@Wdec concurrently on spare CUs.
__global__ __launch_bounds__(256, 2) void gemm1_kernel(
    const unsigned short* __restrict__ A, const float* __restrict__ Bw,
    unsigned short* __restrict__ Cb,
    const float* __restrict__ sth, const float* __restrict__ Wdec,
    float* __restrict__ dec) {
  constexpr int K = 4096, NT = 64;
  constexpr int ASLAB = 8192, BSLAB = 4096;   // bytes per 32-k slab
  __shared__ unsigned short lds_a[128 * 64];  // 16 KB
  __shared__ unsigned short lds_b[64 * 64];   // 8 KB
  const int tid = threadIdx.x;
  const int bid = (int)blockIdx.x;

  if (bid >= 512) {                           // ---- folded dec_accum (32 blocks) ----
    float* ss = (float*)lds_a;                // [32][128] floats = 16 KB
    const int db = bid - 512;
    const int k0 = (db >> 2) * 128;
    for (int i = tid; i < 32 * 128; i += 256) {
      int bb = i >> 7, kk = i & 127;
      ss[bb * 128 + kk] = sth[bb * 1024 + k0 + kk];
    }
    __syncthreads();
    const int j = (db & 3) * 256 + tid;
    float acc2[32];
#pragma unroll
    for (int b = 0; b < 32; ++b) acc2[b] = 0.f;
    for (int kk = 0; kk < 128; ++kk) {
      float w = Wdec[(size_t)(k0 + kk) * 1024 + j];
#pragma unroll
      for (int b = 0; b < 32; ++b) acc2[b] += ss[b * 128 + kk] * w;
    }
    for (int b = 0; b < 32; ++b) atomicAdd(&dec[b * 1024 + j], acc2[b]);
    return;
  }

  const int lane = tid & 63, wave = tid >> 6;
  const int wm = wave >> 1, wn = wave & 1;
  const int quad = lane >> 4, col = lane & 15;
  const int swz = (bid & 7) * 64 + (bid >> 3);   // XCD swizzle over 512
  const int m0 = (swz & 7) * 128;                // SWAPXY: m-tiles fastest
  const int n0 = (swz >> 3) * 64;

  floatx4 acc[4][2] = {};

  const int srow = tid >> 2;
  const int skoff = ((tid & 3) ^ ((tid >> 3) & 3)) * 8;   // XOR chunk swizzle (source)
  const unsigned short* a_ptr = A + (size_t)(m0 + srow) * K + skoff;
  const float* b_src = Bw + (size_t)(n0 + srow) * K + skoff;
  const size_t rowskip = (size_t)64 * K;
  char* const la_dst = (char*)lds_a + tid * 16;
  char* const lb_dst = (char*)lds_b + tid * 16;
  const int cx = (quad ^ ((col >> 1) & 3)) * 16;          // XOR chunk swizzle (read)

  float4 rB0[4], rB1[4];
  auto LOADB = [&](float4* r, int t) {
    const float* p = b_src + (size_t)t * 64;
#pragma unroll
    for (int s = 0; s < 2; ++s) {
      r[2 * s]     = *(const float4*)(p + s * 32);
      r[2 * s + 1] = *(const float4*)(p + s * 32 + 4);
    }
  };
  auto WRITEB = [&](const float4* r) {
#pragma unroll
    for (int s = 0; s < 2; ++s) {
      short8 o;
      o[0] = (short)f2bf_rne(r[2 * s].x);     o[1] = (short)f2bf_rne(r[2 * s].y);
      o[2] = (short)f2bf_rne(r[2 * s].z);     o[3] = (short)f2bf_rne(r[2 * s].w);
      o[4] = (short)f2bf_rne(r[2 * s + 1].x); o[5] = (short)f2bf_rne(r[2 * s + 1].y);
      o[6] = (short)f2bf_rne(r[2 * s + 1].z); o[7] = (short)f2bf_rne(r[2 * s + 1].w);
      *(short8*)(lb_dst + s * BSLAB) = o;
    }
  };
  auto STAGEA = [&](int t) {
    const unsigned short* p = a_ptr + (size_t)t * 64;
#pragma unroll
    for (int h = 0; h < 2; ++h)
#pragma unroll
      for (int s = 0; s < 2; ++s)
        __builtin_amdgcn_global_load_lds((const GLOBAL_AS void*)(p + h * rowskip + s * 32),
                                         (LDS_AS void*)(la_dst + s * ASLAB + h * 4096), 16, 0, 0);
  };
  auto COMPUTE = [&]() {
#pragma unroll
    for (int s = 0; s < 2; ++s) {
      short8 af[4], bf[2];
#pragma unroll
      for (int tf = 0; tf < 4; ++tf)
        af[tf] = *(const short8*)((const char*)lds_a + s * ASLAB +
                                  (wm * 64 + tf * 16 + col) * 64 + cx);
#pragma unroll
      for (int tf = 0; tf < 2; ++tf)
        bf[tf] = *(const short8*)((const char*)lds_b + s * BSLAB +
                                  (wn * 32 + tf * 16 + col) * 64 + cx);
#pragma unroll
      for (int tm = 0; tm < 4; ++tm)
#pragma unroll
        for (int tn = 0; tn < 2; ++tn)
          acc[tm][tn] = __builtin_amdgcn_mfma_f32_16x16x32_bf16(af[tm], bf[tn], acc[tm][tn], 0, 0, 0);
    }
  };
  auto STEP = [&](float4* cur, float4* nxt, int t, bool pf) {
    __syncthreads();                 // readers of prev tile done; prev prefetch drained
    STAGEA(t);                       // gload_lds (A tile)
    WRITEB(cur);                     // cvt + ds_write (regs already valid — no wait)
    if (pf) LOADB(nxt, t + 1);       // prefetch next B slab (overlaps STAGEA latency)
    __syncthreads();                 // full drain: tile ready
    COMPUTE();
  };

  LOADB(rB0, 0);
  for (int t = 0; t < NT; t += 2) {
    STEP(rB0, rB1, t, true);
    STEP(rB1, rB0, t + 1, t + 2 < NT);
  }

#pragma unroll
  for (int tm = 0; tm < 4; ++tm) {
    const int mg = m0 + wm * 64 + tm * 16 + quad * 4;
#pragma unroll
    for (int tn = 0; tn < 2; ++tn) {
      const int ng = n0 + wn * 32 + tn * 16 + col;
#pragma unroll
      for (int r = 0; r < 4; ++r)
        Cb[(size_t)(mg + r) * 4096 + ng] = f2bf_rne(acc[tm][tn][r]);
    }
  }
}

// ---------------- GEMM2: gstar[6272,1024] = gf(fp32 direct) @ C1 + bias1 ------------
// A = gf fp32 reg-staged with fused cast + 1-step prefetch; B = C1T bf16 gload_lds.
// Same corrected __syncthreads() sync as GEMM1.
__global__ __launch_bounds__(256, 2) void gemm2_kernel(
    const float* __restrict__ Af, const unsigned short* __restrict__ BT,
    const float* __restrict__ bias, float* __restrict__ Cf,
    unsigned short* __restrict__ Cb) {
  constexpr int K = 4096, NT = 64, N = 1024;
  constexpr int ASLAB = 8192, BSLAB = 8192;   // bytes per 32-k slab (128 rows x 64 B)
  __shared__ unsigned short lds_a[128 * 64];  // 16 KB
  __shared__ unsigned short lds_b[128 * 64];  // 16 KB
  const int tid = threadIdx.x;
  const int lane = tid & 63, wave = tid >> 6;
  const int wm = wave >> 1, wn = wave & 1;
  const int quad = lane >> 4, col = lane & 15;

  const int gx = (int)gridDim.x;              // 8 (n-tiles)
  const int nwg = gx * (int)gridDim.y;        // 392
  const int bid = (int)blockIdx.y * gx + (int)blockIdx.x;
  const int swz = (bid & 7) * (nwg >> 3) + (bid >> 3);
  const int m0 = (swz / gx) * 128, n0 = (swz % gx) * 128;

  floatx4 acc[4][4] = {};

  const int srow = tid >> 2;
  const int skoff = ((tid & 3) ^ ((tid >> 3) & 3)) * 8;
  const float* a_src = Af + (size_t)(m0 + srow) * K + skoff;
  const unsigned short* b_ptr = BT + (size_t)(n0 + srow) * K + skoff;
  const size_t rowskip = (size_t)64 * K;
  char* const la_dst = (char*)lds_a + tid * 16;
  char* const lb_dst = (char*)lds_b + tid * 16;
  const int cx = (quad ^ ((col >> 1) & 3)) * 16;

  float4 rA0[8], rA1[8];
  auto LOADA = [&](float4* r, int t) {
    const float* p = a_src + (size_t)t * 64;
#pragma unroll
    for (int h = 0; h < 2; ++h)
#pragma unroll
      for (int s = 0; s < 2; ++s) {
        r[h * 4 + 2 * s]     = *(const float4*)(p + h * rowskip + s * 32);
        r[h * 4 + 2 * s + 1] = *(const float4*)(p + h * rowskip + s * 32 + 4);
      }
  };
  auto WRITEA = [&](const float4* r) {
#pragma unroll
    for (int h = 0; h < 2; ++h)
#pragma unroll
      for (int s = 0; s < 2; ++s) {
        const float4 a = r[h * 4 + 2 * s], b = r[h * 4 + 2 * s + 1];
        short8 o;
        o[0] = (short)f2bf_rne(a.x); o[1] = (short)f2bf_rne(a.y);
        o[2] = (short)f2bf_rne(a.z); o[3] = (short)f2bf_rne(a.w);
        o[4] = (short)f2bf_rne(b.x); o[5] = (short)f2bf_rne(b.y);
        o[6] = (short)f2bf_rne(b.z); o[7] = (short)f2bf_rne(b.w);
        *(short8*)(la_dst + s * ASLAB + h * 4096) = o;
      }
  };
  auto STAGEB = [&](int t) {
    const unsigned short* p = b_ptr + (size_t)t * 64;
#pragma unroll
    for (int h = 0; h < 2; ++h)
#pragma unroll
      for (int s = 0; s < 2; ++s)
        __builtin_amdgcn_global_load_lds((const GLOBAL_AS void*)(p + h * rowskip + s * 32),
                                         (LDS_AS void*)(lb_dst + s * BSLAB + h * 4096), 16, 0, 0);
  };
  auto COMPUTE = [&]() {
#pragma unroll
    for (int s = 0; s < 2; ++s) {
      short8 af[4], bf[4];
#pragma unroll
      for (int tf = 0; tf < 4; ++tf)
        af[tf] = *(const short8*)((const char*)lds_a + s * ASLAB +
                                  (wm * 64 + tf * 16 + col) * 64 + cx);
#pragma unroll
      for (int tf = 0; tf < 4; ++tf)
        bf[tf] = *(const short8*)((const char*)lds_b + s * BSLAB +
                                  (wn * 64 + tf * 16 + col) * 64 + cx);
#pragma unroll
      for (int tm = 0; tm < 4; ++tm)
#pragma unroll
        for (int tn = 0; tn < 4; ++tn)
          acc[tm][tn] = __builtin_amdgcn_mfma_f32_16x16x32_bf16(af[tm], bf[tn], acc[tm][tn], 0, 0, 0);
    }
  };
  auto STEP = [&](float4* cur, float4* nxt, int t, bool pf) {
    __syncthreads();                 // readers done; prev prefetch drained
    STAGEB(t);                       // gload_lds (B tile)
    WRITEA(cur);                     // cvt + ds_write (no wait needed)
    if (pf) LOADA(nxt, t + 1);       // prefetch next A slab
    __syncthreads();                 // full drain: tile ready
    COMPUTE();
  };

  LOADA(rA0, 0);
  for (int t = 0; t < NT; t += 2) {
    STEP(rA0, rA1, t, true);
    STEP(rA1, rA0, t + 1, t + 2 < NT);
  }

#pragma unroll
  for (int tm = 0; tm < 4; ++tm) {
    const int mg = m0 + wm * 64 + tm * 16 + quad * 4;
#pragma unroll
    for (int tn = 0; tn < 4; ++tn) {
      const int ng = n0 + wn * 64 + tn * 16 + col;
      const float bv = bias[ng];
#pragma unroll
      for (int r = 0; r < 4; ++r) {
        const float val = acc[tm][tn][r] + bv;
        Cf[(size_t)(mg + r) * N + ng] = val;
        Cb[(size_t)(mg + r) * N + ng] = f2bf_rne(val);
      }
    }
  }
}

// ---------------- GEMM3 (128x64, single-buffer, swizzled) + scores epilogue ---------
__global__ __launch_bounds__(256, 4) void gemm_scores_kernel(
    const unsigned short* __restrict__ A, const unsigned short* __restrict__ BT,
    const float* __restrict__ dec, const float* __restrict__ cov,
    const float* __restrict__ v, float* __restrict__ scores, int M, int N, int K) {
  constexpr int ASLAB = 8192;
  constexpr int BSLAB = 4096;
  __shared__ unsigned short lds_a[128 * 64];
  __shared__ unsigned short lds_b[64 * 64];
  const int tid = threadIdx.x;
  const int lane = tid & 63;
  const int wave = tid >> 6;
  const int wm = wave >> 1, wn = wave & 1;
  const int quad = lane >> 4, col = lane & 15;

  const int gx = (int)gridDim.x;
  const int nwg = gx * (int)gridDim.y;
  const int bid = (int)blockIdx.y * gx + (int)blockIdx.x;
  const int swz = (bid & 7) * (nwg >> 3) + (bid >> 3);
  const int m0 = (swz / gx) * 128, n0 = (swz % gx) * 64;

  floatx4 acc[4][2] = {};

  const int srow = tid >> 2;
  const int skoff = ((tid & 3) ^ ((tid >> 3) & 3)) * 8;
  const unsigned short* a_ptr = A + (size_t)(m0 + srow) * K + skoff;
  const unsigned short* b_ptr = BT + (size_t)(n0 + srow) * K + skoff;
  const size_t rowskip = (size_t)64 * K;
  char* const la_dst = (char*)lds_a + tid * 16;
  char* const lb_dst = (char*)lds_b + tid * 16;
  const int cx = (quad ^ ((col >> 1) & 3)) * 16;

  for (int kt = 0; kt < K; kt += 64) {
    __syncthreads();
#pragma unroll
    for (int h = 0; h < 2; ++h)
#pragma unroll
      for (int s = 0; s < 2; ++s)
        __builtin_amdgcn_global_load_lds((const GLOBAL_AS void*)(a_ptr + h * rowskip + s * 32),
                                         (LDS_AS void*)(la_dst + s * ASLAB + h * 4096), 16, 0, 0);
#pragma unroll
    for (int s = 0; s < 2; ++s)
      __builtin_amdgcn_global_load_lds((const GLOBAL_AS void*)(b_ptr + s * 32),
                                       (LDS_AS void*)(lb_dst + s * BSLAB), 16, 0, 0);
    a_ptr += 64; b_ptr += 64;
    __syncthreads();
#pragma unroll
    for (int s = 0; s < 2; ++s) {
      short8 af[4], bf[2];
#pragma unroll
      for (int tf = 0; tf < 4; ++tf)
        af[tf] = *(const short8*)((const char*)lds_a + s * ASLAB +
                                  (wm * 64 + tf * 16 + col) * 64 + cx);
#pragma unroll
      for (int tf = 0; tf < 2; ++tf)
        bf[tf] = *(const short8*)((const char*)lds_b + s * BSLAB +
                                  (wn * 32 + tf * 16 + col) * 64 + cx);
#pragma unroll
      for (int tm = 0; tm < 4; ++tm)
#pragma unroll
        for (int tn = 0; tn < 2; ++tn)
          acc[tm][tn] = __builtin_amdgcn_mfma_f32_16x16x32_bf16(af[tm], bf[tn], acc[tm][tn], 0, 0, 0);
    }
  }

  const int n_base = n0 + wn * 32;
  float vv[2];
#pragma unroll
  for (int tn = 0; tn < 2; ++tn) vv[tn] = v[n_base + tn * 16 + col];
#pragma unroll
  for (int tm = 0; tm < 4; ++tm) {
#pragma unroll
    for (int r = 0; r < 4; ++r) {
      const int row = m0 + wm * 64 + tm * 16 + quad * 4 + r;
      const int b = row / 196;
      const float cw = cov[row];
      const float* dr = dec + b * 1024 + n_base;
      float s = 0.f;
#pragma unroll
      for (int tn = 0; tn < 2; ++tn)
        s += tanhf(acc[tm][tn][r] + dr[tn * 16 + col] + cw) * vv[tn];
      s += __shfl_xor(s, 1, 64);
      s += __shfl_xor(s, 2, 64);
      s += __shfl_xor(s, 4, 64);
      s += __shfl_xor(s, 8, 64);
      if ((lane & 15) == 0) atomicAdd(&scores[row], s);
    }
  }
}

// ---------------- softmax over 196 regions: alpha + coverage outputs ----------------
__global__ void softmax_kernel(const float* __restrict__ scores, const float* __restrict__ cov,
                               float* __restrict__ alpha_ws, float* __restrict__ out) {
  const int b = blockIdx.x, tid = threadIdx.x;
  const int lane = tid & 63, wid = tid >> 6;
  __shared__ float red[8];
  float s = (tid < 196) ? scores[b * 196 + tid] : -1e30f;
  float m = s;
  for (int off = 32; off > 0; off >>= 1) m = fmaxf(m, __shfl_xor(m, off, 64));
  if (lane == 0) red[wid] = m;
  __syncthreads();
  m = fmaxf(fmaxf(red[0], red[1]), fmaxf(red[2], red[3]));
  float e = (tid < 196) ? __expf(s - m) : 0.f;
  float t = e;
  for (int off = 32; off > 0; off >>= 1) t += __shfl_xor(t, off, 64);
  if (lane == 0) red[4 + wid] = t;
  __syncthreads();
  const float tot = red[4] + red[5] + red[6] + red[7];
  const float a = e / tot;
  if (tid < 196) {
    alpha_ws[b * 196 + tid] = a;
    out[32768 + b * 196 + tid] = cov[b * 196 + tid] + a;   // coverage_new
    out[32768 + 6272 + b * 196 + tid] = a;                 // alpha_a
  }
}

// ---------------- context: c_img[b, :] = sum_t alpha[b,t] * gstar[b,t,:] ------------
__global__ __launch_bounds__(256) void ctx_kernel(const float* __restrict__ alpha,
                                                  const float* __restrict__ gstar,
                                                  float* __restrict__ out) {
  const int b = blockIdx.y;
  const int colbase = blockIdx.x * 128;
  const int c = threadIdx.x & 127;
  const int half = threadIdx.x >> 7;
  const float* g = gstar + ((size_t)b * 196 + half * 98) * 1024 + colbase + c;
  const float* al = alpha + b * 196 + half * 98;
  float acc = 0.f;
#pragma unroll 7
  for (int t = 0; t < 98; ++t) acc += al[t] * g[(size_t)t * 1024];
  __shared__ float part[256];
  part[threadIdx.x] = acc;
  __syncthreads();
  if (threadIdx.x < 128)
    out[b * 1024 + colbase + threadIdx.x] = part[threadIdx.x] + part[threadIdx.x + 128];
}

// ---------------- launch ----------------
extern "C" void kernel_launch(void* const* d_in, const int* in_sizes, int n_in,
                              void* d_out, int out_size, void* d_ws, size_t ws_size,
                              hipStream_t stream) {
  (void)in_sizes; (void)n_in; (void)out_size; (void)ws_size;
  const float* gf   = (const float*)d_in[0];   // [6272, 4096]
  const float* sth  = (const float*)d_in[1];   // [32, 1024]
  const float* cov  = (const float*)d_in[2];   // [6272]
  const float* Wg   = (const float*)d_in[3];   // [4096, 4096]
  const float* bg   = (const float*)d_in[4];   // [4096]
  const float* Gs   = (const float*)d_in[5];   // [4096, 1024]
  const float* bgs  = (const float*)d_in[6];   // [1024]
  const float* Wgs  = (const float*)d_in[7];   // [1024, 1024]
  const float* Wdec = (const float*)d_in[8];   // [1024, 1024]
  const float* bdec = (const float*)d_in[9];   // [1024]
  const float* v    = (const float*)d_in[10];  // [1024]
  float* out = (float*)d_out;

  char* ws = (char*)d_ws;
  // Memory map (all disjoint — gf/Wg read directly from inputs):
  unsigned short* GsT     = (unsigned short*)(ws + 0);          //  8.39 MB
  unsigned short* C1T_b   = (unsigned short*)(ws + 8388608);    //  8.39 MB
  unsigned short* WgsT    = (unsigned short*)(ws + 16777216);   //  2.10 MB
  float*          gstar_f = (float*)(ws + 18874368);            // 25.69 MB
  unsigned short* gstar_b = (unsigned short*)(ws + 44564480);   // 12.85 MB
  float*          bias1   = (float*)(ws + 57409536);
  float*          dec     = (float*)(ws + 57413632);
  float*          scores  = (float*)(ws + 57544704);
  float*          alpha   = (float*)(ws + 57569792);

  // 1. bias1 init (bgs) + prep0: Gs/Wgs transposes, bias1 accum, dec init, zero scores
  hipMemcpyAsync(bias1, bgs, 4096, hipMemcpyDeviceToDevice, stream);
  prep0_kernel<<<5319, 256, 0, stream>>>(Gs, GsT, Wgs, WgsT, bg, bias1, bdec, dec, scores);
  // 2. GEMM1 (Wg fp32 fused-cast staging) + folded dec_accum. 512 tile + 32 dec blocks.
  gemm1_kernel<<<544, 256, 0, stream>>>(GsT, Wg, C1T_b, sth, Wdec, dec);
  // 3. GEMM2 (gf fp32 fused-cast staging): gstar = gf @ C1 + bias1, f32 + bf16 out.
  gemm2_kernel<<<dim3(8, 49), 256, 0, stream>>>(gf, C1T_b, bias1, gstar_f, gstar_b);
  // 4. GEMM3 fused with scores epilogue. 784 blocks.
  gemm_scores_kernel<<<dim3(16, 49), 256, 0, stream>>>(
      gstar_b, WgsT, dec, cov, v, scores, 6272, 1024, 1024);
  // 5. softmax (alpha + coverage outputs), then parallel context
  softmax_kernel<<<32, 256, 0, stream>>>(scores, cov, alpha, out);
  ctx_kernel<<<dim3(8, 32), 256, 0, stream>>>(alpha, gstar_f, out);
}

// Round 11
// 452.637 us; speedup vs baseline: 1.5103x; 1.0223x over previous
//
#include <hip/hip_runtime.h>
#include <hip/hip_bf16.h>

typedef __attribute__((ext_vector_type(8))) short short8;
typedef __attribute__((ext_vector_type(4))) float floatx4;

#define GLOBAL_AS __attribute__((address_space(1)))
#define LDS_AS    __attribute__((address_space(3)))

// s_waitcnt imm: vmcnt<=n, lgkmcnt==0, expcnt unconstrained (gfx9 layout)
#define WAITCNT_VL0(n) (0x0070 | ((n) & 15) | ((((n) >> 4) & 3) << 14))

__device__ __forceinline__ unsigned short f2bf_rne(float x) {
  unsigned int u = __float_as_uint(x);
  u += 0x7fffu + ((u >> 16) & 1u);
  return (unsigned short)(u >> 16);
}

__device__ __forceinline__ void trans32_body(const float* __restrict__ in,
                                             unsigned short* __restrict__ out,
                                             int R, int C, int bx, int by) {
  __shared__ unsigned short tile[32][33];
  int tx = threadIdx.x & 31, ty = threadIdx.x >> 5;
  int r0 = by * 32, c0 = bx * 32;
#pragma unroll
  for (int j = 0; j < 32; j += 8)
    tile[ty + j][tx] = f2bf_rne(in[(size_t)(r0 + ty + j) * C + c0 + tx]);
  __syncthreads();
#pragma unroll
  for (int j = 0; j < 32; j += 8)
    out[(size_t)(c0 + ty + j) * R + r0 + tx] = tile[tx][ty + j];
}

// ---------------- prep0: transpose Gs, transpose Wgs, bias1 accum, dec init, zero ---
// bias1 pre-initialized to bgs via hipMemcpyAsync before this launch.
__global__ void prep0_kernel(const float* __restrict__ Gs, unsigned short* __restrict__ GsT,
                             const float* __restrict__ Wgs, unsigned short* __restrict__ WgsT,
                             const float* __restrict__ bg, float* __restrict__ bias1,
                             const float* __restrict__ bdec, float* __restrict__ dec,
                             float* __restrict__ scores) {
  const int b = blockIdx.x;
  if (b < 4096) {
    trans32_body(Gs, GsT, 4096, 1024, b & 31, b >> 5);
  } else if (b < 5120) {
    int bb = b - 4096;
    trans32_body(Wgs, WgsT, 1024, 1024, bb & 31, bb >> 5);
  } else if (b < 5184) {
    int bb = b - 5120;                        // 64 blocks: 4 j-chunks x 16 k-chunks
    int j = (bb & 3) * 256 + threadIdx.x;
    int k0 = (bb >> 2) * 256;
    float acc = 0.f;
    for (int k = 0; k < 256; ++k) acc += bg[k0 + k] * Gs[(size_t)(k0 + k) * 1024 + j];
    atomicAdd(&bias1[j], acc);
  } else if (b < 5312) {
    int i = (b - 5184) * 256 + threadIdx.x;   // 128 blocks: dec init (32x1024)
    dec[i] = bdec[i & 1023];
  } else {
    int i = (b - 5312) * 256 + threadIdx.x;   // 7 blocks zero 6272 floats
    if (i < 1568) ((float4*)scores)[i] = make_float4(0.f, 0.f, 0.f, 0.f);
  }
}

// ---------------- GEMM1 + folded dec: C1T[1024,4096] = GsT @ Wg^T (Wg fp32 direct) --
// Fused-cast reg-staging (R10-proven correct) + PINNED counted-vmcnt pipeline:
// the R9 race was the scheduler hoisting prefetch loads above global_load_lds,
// inverting the FIFO my vmcnt(N) counted. Fix: sched_barrier(0) directly after the
// STAGE group pins issue order [STAGE][prefetch]. Top s_barrier is RAW (no drain) so
// the prefetch issued last step survives it; WRITE's operands get a compiler-auto
// RAW wait (drains only the year-old prefetch); explicit vmcnt(4)+lgkmcnt(0) drains
// exactly STAGE+ds_writes, leaving the new prefetch in flight through COMPUTE.
__global__ __launch_bounds__(256, 2) void gemm1_kernel(
    const unsigned short* __restrict__ A, const float* __restrict__ Bw,
    unsigned short* __restrict__ Cb,
    const float* __restrict__ sth, const float* __restrict__ Wdec,
    float* __restrict__ dec) {
  constexpr int K = 4096, NT = 64;
  constexpr int ASLAB = 8192, BSLAB = 4096;   // bytes per 32-k slab
  __shared__ unsigned short lds_a[128 * 64];  // 16 KB
  __shared__ unsigned short lds_b[64 * 64];   // 8 KB
  const int tid = threadIdx.x;
  const int bid = (int)blockIdx.x;

  if (bid >= 512) {                           // ---- folded dec_accum (32 blocks) ----
    float* ss = (float*)lds_a;                // [32][128] floats = 16 KB
    const int db = bid - 512;
    const int k0 = (db >> 2) * 128;
    for (int i = tid; i < 32 * 128; i += 256) {
      int bb = i >> 7, kk = i & 127;
      ss[bb * 128 + kk] = sth[bb * 1024 + k0 + kk];
    }
    __syncthreads();
    const int j = (db & 3) * 256 + tid;
    float acc2[32];
#pragma unroll
    for (int b = 0; b < 32; ++b) acc2[b] = 0.f;
    for (int kk = 0; kk < 128; ++kk) {
      float w = Wdec[(size_t)(k0 + kk) * 1024 + j];
#pragma unroll
      for (int b = 0; b < 32; ++b) acc2[b] += ss[b * 128 + kk] * w;
    }
    for (int b = 0; b < 32; ++b) atomicAdd(&dec[b * 1024 + j], acc2[b]);
    return;
  }

  const int lane = tid & 63, wave = tid >> 6;
  const int wm = wave >> 1, wn = wave & 1;
  const int quad = lane >> 4, col = lane & 15;
  const int swz = (bid & 7) * 64 + (bid >> 3);   // XCD swizzle over 512
  const int m0 = (swz & 7) * 128;                // SWAPXY: m-tiles fastest
  const int n0 = (swz >> 3) * 64;

  floatx4 acc[4][2] = {};

  const int srow = tid >> 2;
  const int skoff = ((tid & 3) ^ ((tid >> 3) & 3)) * 8;   // XOR chunk swizzle (source)
  const unsigned short* a_ptr = A + (size_t)(m0 + srow) * K + skoff;
  const float* b_src = Bw + (size_t)(n0 + srow) * K + skoff;
  const size_t rowskip = (size_t)64 * K;
  char* const la_dst = (char*)lds_a + tid * 16;
  char* const lb_dst = (char*)lds_b + tid * 16;
  const int cx = (quad ^ ((col >> 1) & 3)) * 16;          // XOR chunk swizzle (read)

  float4 rB0[4], rB1[4];
  auto LOADB = [&](float4* r, int t) {
    const float* p = b_src + (size_t)t * 64;
#pragma unroll
    for (int s = 0; s < 2; ++s) {
      r[2 * s]     = *(const float4*)(p + s * 32);
      r[2 * s + 1] = *(const float4*)(p + s * 32 + 4);
    }
  };
  auto WRITEB = [&](const float4* r) {
#pragma unroll
    for (int s = 0; s < 2; ++s) {
      short8 o;
      o[0] = (short)f2bf_rne(r[2 * s].x);     o[1] = (short)f2bf_rne(r[2 * s].y);
      o[2] = (short)f2bf_rne(r[2 * s].z);     o[3] = (short)f2bf_rne(r[2 * s].w);
      o[4] = (short)f2bf_rne(r[2 * s + 1].x); o[5] = (short)f2bf_rne(r[2 * s + 1].y);
      o[6] = (short)f2bf_rne(r[2 * s + 1].z); o[7] = (short)f2bf_rne(r[2 * s + 1].w);
      *(short8*)(lb_dst + s * BSLAB) = o;
    }
  };
  auto STAGEA = [&](int t) {
    const unsigned short* p = a_ptr + (size_t)t * 64;
#pragma unroll
    for (int h = 0; h < 2; ++h)
#pragma unroll
      for (int s = 0; s < 2; ++s)
        __builtin_amdgcn_global_load_lds((const GLOBAL_AS void*)(p + h * rowskip + s * 32),
                                         (LDS_AS void*)(la_dst + s * ASLAB + h * 4096), 16, 0, 0);
  };
  auto COMPUTE = [&]() {
#pragma unroll
    for (int s = 0; s < 2; ++s) {
      short8 af[4], bf[2];
#pragma unroll
      for (int tf = 0; tf < 4; ++tf)
        af[tf] = *(const short8*)((const char*)lds_a + s * ASLAB +
                                  (wm * 64 + tf * 16 + col) * 64 + cx);
#pragma unroll
      for (int tf = 0; tf < 2; ++tf)
        bf[tf] = *(const short8*)((const char*)lds_b + s * BSLAB +
                                  (wn * 32 + tf * 16 + col) * 64 + cx);
#pragma unroll
      for (int tm = 0; tm < 4; ++tm)
#pragma unroll
        for (int tn = 0; tn < 2; ++tn)
          acc[tm][tn] = __builtin_amdgcn_mfma_f32_16x16x32_bf16(af[tm], bf[tn], acc[tm][tn], 0, 0, 0);
    }
  };
  auto STEP = [&](float4* cur, float4* nxt, int t, bool pf) {
    asm volatile("" ::: "memory");
    __builtin_amdgcn_s_barrier();            // RAW barrier: readers of prev tile done;
    asm volatile("" ::: "memory");           // prev prefetch NOT drained (the point)
    STAGEA(t);                               // 4 gload_lds — FIRST in vm FIFO
    __builtin_amdgcn_sched_barrier(0);       // pin: prefetch cannot hoist above STAGE
    WRITEB(cur);                             // auto RAW wait drains prev LOADB only
    if (pf) LOADB(nxt, t + 1);               // prefetch: stays in flight past barrier
    __builtin_amdgcn_sched_barrier(0);
    if (pf) __builtin_amdgcn_s_waitcnt(WAITCNT_VL0(4));   // drain STAGEA + ds_writes
    else    __builtin_amdgcn_s_waitcnt(WAITCNT_VL0(0));
    __builtin_amdgcn_s_barrier();            // tile ready
    asm volatile("" ::: "memory");
    __builtin_amdgcn_sched_barrier(0);
    COMPUTE();
    __builtin_amdgcn_sched_barrier(0);
  };

  LOADB(rB0, 0);
  for (int t = 0; t < NT; t += 2) {
    STEP(rB0, rB1, t, true);
    STEP(rB1, rB0, t + 1, t + 2 < NT);
  }

#pragma unroll
  for (int tm = 0; tm < 4; ++tm) {
    const int mg = m0 + wm * 64 + tm * 16 + quad * 4;
#pragma unroll
    for (int tn = 0; tn < 2; ++tn) {
      const int ng = n0 + wn * 32 + tn * 16 + col;
#pragma unroll
      for (int r = 0; r < 4; ++r)
        Cb[(size_t)(mg + r) * 4096 + ng] = f2bf_rne(acc[tm][tn][r]);
    }
  }
}

// ---------------- GEMM2: gstar[6272,1024] = gf(fp32 direct) @ C1 + bias1 ------------
// Same pinned counted-vmcnt STEP; FIFO trace: entry [LOADA(t):8]; +STAGEB -> [8][4];
// WRITEA auto-RAW drains LOADA(t) -> [STAGEB:4]; +LOADA(t+1) -> [4][8];
// explicit vmcnt(8) drains STAGEB, leaving the gf prefetch in flight through COMPUTE
// and the next barrier (a full K-step ~ covers the ~900cy HBM latency).
__global__ __launch_bounds__(256, 2) void gemm2_kernel(
    const float* __restrict__ Af, const unsigned short* __restrict__ BT,
    const float* __restrict__ bias, float* __restrict__ Cf,
    unsigned short* __restrict__ Cb) {
  constexpr int K = 4096, NT = 64, N = 1024;
  constexpr int ASLAB = 8192, BSLAB = 8192;   // bytes per 32-k slab (128 rows x 64 B)
  __shared__ unsigned short lds_a[128 * 64];  // 16 KB
  __shared__ unsigned short lds_b[128 * 64];  // 16 KB
  const int tid = threadIdx.x;
  const int lane = tid & 63, wave = tid >> 6;
  const int wm = wave >> 1, wn = wave & 1;
  const int quad = lane >> 4, col = lane & 15;

  const int gx = (int)gridDim.x;              // 8 (n-tiles)
  const int nwg = gx * (int)gridDim.y;        // 392
  const int bid = (int)blockIdx.y * gx + (int)blockIdx.x;
  const int swz = (bid & 7) * (nwg >> 3) + (bid >> 3);
  const int m0 = (swz / gx) * 128, n0 = (swz % gx) * 128;

  floatx4 acc[4][4] = {};

  const int srow = tid >> 2;
  const int skoff = ((tid & 3) ^ ((tid >> 3) & 3)) * 8;
  const float* a_src = Af + (size_t)(m0 + srow) * K + skoff;
  const unsigned short* b_ptr = BT + (size_t)(n0 + srow) * K + skoff;
  const size_t rowskip = (size_t)64 * K;
  char* const la_dst = (char*)lds_a + tid * 16;
  char* const lb_dst = (char*)lds_b + tid * 16;
  const int cx = (quad ^ ((col >> 1) & 3)) * 16;

  float4 rA0[8], rA1[8];
  auto LOADA = [&](float4* r, int t) {
    const float* p = a_src + (size_t)t * 64;
#pragma unroll
    for (int h = 0; h < 2; ++h)
#pragma unroll
      for (int s = 0; s < 2; ++s) {
        r[h * 4 + 2 * s]     = *(const float4*)(p + h * rowskip + s * 32);
        r[h * 4 + 2 * s + 1] = *(const float4*)(p + h * rowskip + s * 32 + 4);
      }
  };
  auto WRITEA = [&](const float4* r) {
#pragma unroll
    for (int h = 0; h < 2; ++h)
#pragma unroll
      for (int s = 0; s < 2; ++s) {
        const float4 a = r[h * 4 + 2 * s], b = r[h * 4 + 2 * s + 1];
        short8 o;
        o[0] = (short)f2bf_rne(a.x); o[1] = (short)f2bf_rne(a.y);
        o[2] = (short)f2bf_rne(a.z); o[3] = (short)f2bf_rne(a.w);
        o[4] = (short)f2bf_rne(b.x); o[5] = (short)f2bf_rne(b.y);
        o[6] = (short)f2bf_rne(b.z); o[7] = (short)f2bf_rne(b.w);
        *(short8*)(la_dst + s * ASLAB + h * 4096) = o;
      }
  };
  auto STAGEB = [&](int t) {
    const unsigned short* p = b_ptr + (size_t)t * 64;
#pragma unroll
    for (int h = 0; h < 2; ++h)
#pragma unroll
      for (int s = 0; s < 2; ++s)
        __builtin_amdgcn_global_load_lds((const GLOBAL_AS void*)(p + h * rowskip + s * 32),
                                         (LDS_AS void*)(lb_dst + s * BSLAB + h * 4096), 16, 0, 0);
  };
  auto COMPUTE = [&]() {
#pragma unroll
    for (int s = 0; s < 2; ++s) {
      short8 af[4], bf[4];
#pragma unroll
      for (int tf = 0; tf < 4; ++tf)
        af[tf] = *(const short8*)((const char*)lds_a + s * ASLAB +
                                  (wm * 64 + tf * 16 + col) * 64 + cx);
#pragma unroll
      for (int tf = 0; tf < 4; ++tf)
        bf[tf] = *(const short8*)((const char*)lds_b + s * BSLAB +
                                  (wn * 64 + tf * 16 + col) * 64 + cx);
#pragma unroll
      for (int tm = 0; tm < 4; ++tm)
#pragma unroll
        for (int tn = 0; tn < 4; ++tn)
          acc[tm][tn] = __builtin_amdgcn_mfma_f32_16x16x32_bf16(af[tm], bf[tn], acc[tm][tn], 0, 0, 0);
    }
  };
  auto STEP = [&](float4* cur, float4* nxt, int t, bool pf) {
    asm volatile("" ::: "memory");
    __builtin_amdgcn_s_barrier();            // RAW barrier (no vm drain)
    asm volatile("" ::: "memory");
    STAGEB(t);                               // 4 gload_lds — FIRST in vm FIFO
    __builtin_amdgcn_sched_barrier(0);       // pin issue order
    WRITEA(cur);                             // auto RAW wait drains prev LOADA only
    if (pf) LOADA(nxt, t + 1);               // prefetch survives the next barrier
    __builtin_amdgcn_sched_barrier(0);
    if (pf) __builtin_amdgcn_s_waitcnt(WAITCNT_VL0(8));   // drain STAGEB + ds_writes
    else    __builtin_amdgcn_s_waitcnt(WAITCNT_VL0(0));
    __builtin_amdgcn_s_barrier();            // tile ready
    asm volatile("" ::: "memory");
    __builtin_amdgcn_sched_barrier(0);
    COMPUTE();
    __builtin_amdgcn_sched_barrier(0);
  };

  LOADA(rA0, 0);
  for (int t = 0; t < NT; t += 2) {
    STEP(rA0, rA1, t, true);
    STEP(rA1, rA0, t + 1, t + 2 < NT);
  }

#pragma unroll
  for (int tm = 0; tm < 4; ++tm) {
    const int mg = m0 + wm * 64 + tm * 16 + quad * 4;
#pragma unroll
    for (int tn = 0; tn < 4; ++tn) {
      const int ng = n0 + wn * 64 + tn * 16 + col;
      const float bv = bias[ng];
#pragma unroll
      for (int r = 0; r < 4; ++r) {
        const float val = acc[tm][tn][r] + bv;
        Cf[(size_t)(mg + r) * N + ng] = val;
        Cb[(size_t)(mg + r) * N + ng] = f2bf_rne(val);
      }
    }
  }
}

// ---------------- GEMM3 (128x64, single-buffer, swizzled) + scores epilogue ---------
__global__ __launch_bounds__(256, 4) void gemm_scores_kernel(
    const unsigned short* __restrict__ A, const unsigned short* __restrict__ BT,
    const float* __restrict__ dec, const float* __restrict__ cov,
    const float* __restrict__ v, float* __restrict__ scores, int M, int N, int K) {
  constexpr int ASLAB = 8192;
  constexpr int BSLAB = 4096;
  __shared__ unsigned short lds_a[128 * 64];
  __shared__ unsigned short lds_b[64 * 64];
  const int tid = threadIdx.x;
  const int lane = tid & 63;
  const int wave = tid >> 6;
  const int wm = wave >> 1, wn = wave & 1;
  const int quad = lane >> 4, col = lane & 15;

  const int gx = (int)gridDim.x;
  const int nwg = gx * (int)gridDim.y;
  const int bid = (int)blockIdx.y * gx + (int)blockIdx.x;
  const int swz = (bid & 7) * (nwg >> 3) + (bid >> 3);
  const int m0 = (swz / gx) * 128, n0 = (swz % gx) * 64;

  floatx4 acc[4][2] = {};

  const int srow = tid >> 2;
  const int skoff = ((tid & 3) ^ ((tid >> 3) & 3)) * 8;
  const unsigned short* a_ptr = A + (size_t)(m0 + srow) * K + skoff;
  const unsigned short* b_ptr = BT + (size_t)(n0 + srow) * K + skoff;
  const size_t rowskip = (size_t)64 * K;
  char* const la_dst = (char*)lds_a + tid * 16;
  char* const lb_dst = (char*)lds_b + tid * 16;
  const int cx = (quad ^ ((col >> 1) & 3)) * 16;

  for (int kt = 0; kt < K; kt += 64) {
    __syncthreads();
#pragma unroll
    for (int h = 0; h < 2; ++h)
#pragma unroll
      for (int s = 0; s < 2; ++s)
        __builtin_amdgcn_global_load_lds((const GLOBAL_AS void*)(a_ptr + h * rowskip + s * 32),
                                         (LDS_AS void*)(la_dst + s * ASLAB + h * 4096), 16, 0, 0);
#pragma unroll
    for (int s = 0; s < 2; ++s)
      __builtin_amdgcn_global_load_lds((const GLOBAL_AS void*)(b_ptr + s * 32),
                                       (LDS_AS void*)(lb_dst + s * BSLAB), 16, 0, 0);
    a_ptr += 64; b_ptr += 64;
    __syncthreads();
#pragma unroll
    for (int s = 0; s < 2; ++s) {
      short8 af[4], bf[2];
#pragma unroll
      for (int tf = 0; tf < 4; ++tf)
        af[tf] = *(const short8*)((const char*)lds_a + s * ASLAB +
                                  (wm * 64 + tf * 16 + col) * 64 + cx);
#pragma unroll
      for (int tf = 0; tf < 2; ++tf)
        bf[tf] = *(const short8*)((const char*)lds_b + s * BSLAB +
                                  (wn * 32 + tf * 16 + col) * 64 + cx);
#pragma unroll
      for (int tm = 0; tm < 4; ++tm)
#pragma unroll
        for (int tn = 0; tn < 2; ++tn)
          acc[tm][tn] = __builtin_amdgcn_mfma_f32_16x16x32_bf16(af[tm], bf[tn], acc[tm][tn], 0, 0, 0);
    }
  }

  const int n_base = n0 + wn * 32;
  float vv[2];
#pragma unroll
  for (int tn = 0; tn < 2; ++tn) vv[tn] = v[n_base + tn * 16 + col];
#pragma unroll
  for (int tm = 0; tm < 4; ++tm) {
#pragma unroll
    for (int r = 0; r < 4; ++r) {
      const int row = m0 + wm * 64 + tm * 16 + quad * 4 + r;
      const int b = row / 196;
      const float cw = cov[row];
      const float* dr = dec + b * 1024 + n_base;
      float s = 0.f;
#pragma unroll
      for (int tn = 0; tn < 2; ++tn)
        s += tanhf(acc[tm][tn][r] + dr[tn * 16 + col] + cw) * vv[tn];
      s += __shfl_xor(s, 1, 64);
      s += __shfl_xor(s, 2, 64);
      s += __shfl_xor(s, 4, 64);
      s += __shfl_xor(s, 8, 64);
      if ((lane & 15) == 0) atomicAdd(&scores[row], s);
    }
  }
}

// ---------------- softmax over 196 regions: alpha + coverage outputs ----------------
__global__ void softmax_kernel(const float* __restrict__ scores, const float* __restrict__ cov,
                               float* __restrict__ alpha_ws, float* __restrict__ out) {
  const int b = blockIdx.x, tid = threadIdx.x;
  const int lane = tid & 63, wid = tid >> 6;
  __shared__ float red[8];
  float s = (tid < 196) ? scores[b * 196 + tid] : -1e30f;
  float m = s;
  for (int off = 32; off > 0; off >>= 1) m = fmaxf(m, __shfl_xor(m, off, 64));
  if (lane == 0) red[wid] = m;
  __syncthreads();
  m = fmaxf(fmaxf(red[0], red[1]), fmaxf(red[2], red[3]));
  float e = (tid < 196) ? __expf(s - m) : 0.f;
  float t = e;
  for (int off = 32; off > 0; off >>= 1) t += __shfl_xor(t, off, 64);
  if (lane == 0) red[4 + wid] = t;
  __syncthreads();
  const float tot = red[4] + red[5] + red[6] + red[7];
  const float a = e / tot;
  if (tid < 196) {
    alpha_ws[b * 196 + tid] = a;
    out[32768 + b * 196 + tid] = cov[b * 196 + tid] + a;   // coverage_new
    out[32768 + 6272 + b * 196 + tid] = a;                 // alpha_a
  }
}

// ---------------- context: c_img[b, :] = sum_t alpha[b,t] * gstar[b,t,:] ------------
__global__ __launch_bounds__(256) void ctx_kernel(const float* __restrict__ alpha,
                                                  const float* __restrict__ gstar,
                                                  float* __restrict__ out) {
  const int b = blockIdx.y;
  const int colbase = blockIdx.x * 128;
  const int c = threadIdx.x & 127;
  const int half = threadIdx.x >> 7;
  const float* g = gstar + ((size_t)b * 196 + half * 98) * 1024 + colbase + c;
  const float* al = alpha + b * 196 + half * 98;
  float acc = 0.f;
#pragma unroll 7
  for (int t = 0; t < 98; ++t) acc += al[t] * g[(size_t)t * 1024];
  __shared__ float part[256];
  part[threadIdx.x] = acc;
  __syncthreads();
  if (threadIdx.x < 128)
    out[b * 1024 + colbase + threadIdx.x] = part[threadIdx.x] + part[threadIdx.x + 128];
}

// ---------------- launch ----------------
extern "C" void kernel_launch(void* const* d_in, const int* in_sizes, int n_in,
                              void* d_out, int out_size, void* d_ws, size_t ws_size,
                              hipStream_t stream) {
  (void)in_sizes; (void)n_in; (void)out_size; (void)ws_size;
  const float* gf   = (const float*)d_in[0];   // [6272, 4096]
  const float* sth  = (const float*)d_in[1];   // [32, 1024]
  const float* cov  = (const float*)d_in[2];   // [6272]
  const float* Wg   = (const float*)d_in[3];   // [4096, 4096]
  const float* bg   = (const float*)d_in[4];   // [4096]
  const float* Gs   = (const float*)d_in[5];   // [4096, 1024]
  const float* bgs  = (const float*)d_in[6];   // [1024]
  const float* Wgs  = (const float*)d_in[7];   // [1024, 1024]
  const float* Wdec = (const float*)d_in[8];   // [1024, 1024]
  const float* bdec = (const float*)d_in[9];   // [1024]
  const float* v    = (const float*)d_in[10];  // [1024]
  float* out = (float*)d_out;

  char* ws = (char*)d_ws;
  // Memory map (all disjoint — gf/Wg read directly from inputs):
  unsigned short* GsT     = (unsigned short*)(ws + 0);          //  8.39 MB
  unsigned short* C1T_b   = (unsigned short*)(ws + 8388608);    //  8.39 MB
  unsigned short* WgsT    = (unsigned short*)(ws + 16777216);   //  2.10 MB
  float*          gstar_f = (float*)(ws + 18874368);            // 25.69 MB
  unsigned short* gstar_b = (unsigned short*)(ws + 44564480);   // 12.85 MB
  float*          bias1   = (float*)(ws + 57409536);
  float*          dec     = (float*)(ws + 57413632);
  float*          scores  = (float*)(ws + 57544704);
  float*          alpha   = (float*)(ws + 57569792);

  // 1. bias1 init (bgs) + prep0: Gs/Wgs transposes, bias1 accum, dec init, zero scores
  hipMemcpyAsync(bias1, bgs, 4096, hipMemcpyDeviceToDevice, stream);
  prep0_kernel<<<5319, 256, 0, stream>>>(Gs, GsT, Wgs, WgsT, bg, bias1, bdec, dec, scores);
  // 2. GEMM1 (Wg fp32 fused-cast staging) + folded dec_accum. 512 tile + 32 dec blocks.
  gemm1_kernel<<<544, 256, 0, stream>>>(GsT, Wg, C1T_b, sth, Wdec, dec);
  // 3. GEMM2 (gf fp32 fused-cast staging): gstar = gf @ C1 + bias1, f32 + bf16 out.
  gemm2_kernel<<<dim3(8, 49), 256, 0, stream>>>(gf, C1T_b, bias1, gstar_f, gstar_b);
  // 4. GEMM3 fused with scores epilogue. 784 blocks.
  gemm_scores_kernel<<<dim3(16, 49), 256, 0, stream>>>(
      gstar_b, WgsT, dec, cov, v, scores, 6272, 1024, 1024);
  // 5. softmax (alpha + coverage outputs), then parallel context
  softmax_kernel<<<32, 256, 0, stream>>>(scores, cov, alpha, out);
  ctx_kernel<<<dim3(8, 32), 256, 0, stream>>>(alpha, gstar_f, out);
}